// Round 1
// baseline (5299.738 us; speedup 1.0000x reference)
//
#include <hip/hip_runtime.h>

// ---------------- problem constants ----------------
constexpr int B_  = 2;
constexpr int C_  = 256;
constexpr int H_  = 100;
constexpr int W_  = 152;
constexpr int HW_ = H_ * W_;          // 15200
constexpr int GN_G = 32;              // 8 ch / group
constexpr int K9 = 9;
constexpr int CK = C_ * K9;           // 2304

constexpr int TH = 4, TW = 8;         // output tile 4x8 = 32 px (exact: 100/4, 152/8)
constexpr int NPX = TH * TW;          // 32

constexpr int OFF_INIT = B_ * 80 * HW_;              // 2,432,000
constexpr int OFF_REF  = OFF_INIT + B_ * 18 * HW_;   // 2,979,200

// ---------------- weight transpose: [256][2304] -> [2304][256] ----------------
__global__ __launch_bounds__(256) void transpose_w_kernel(
    const float* __restrict__ w, float* __restrict__ wt)
{
    __shared__ float t[64][65];
    const int lane = threadIdx.x & 63, grp = threadIdx.x >> 6;
    const int o0 = blockIdx.x * 64;    // 4 tiles
    const int k0 = blockIdx.y * 64;    // 36 tiles
#pragma unroll
    for (int j = 0; j < 16; j++) {
        int o = o0 + j * 4 + grp;
        t[j * 4 + grp][lane] = w[(size_t)o * CK + k0 + lane];
    }
    __syncthreads();
#pragma unroll
    for (int j = 0; j < 16; j++) {
        int k = k0 + j * 4 + grp;
        wt[(size_t)k * C_ + o0 + lane] = t[lane][j * 4 + grp];
    }
}

// ---------------- 1x1 weight transpose: [O][256] -> [256][OP] zero-padded ----------------
__global__ void transpose_w1_kernel(const float* __restrict__ w, float* __restrict__ wt,
                                    int O, int OP)
{
    int c = blockIdx.x;
    int o = threadIdx.x;
    if (o < OP) wt[c * OP + o] = (o < O) ? w[o * C_ + c] : 0.f;
}

// ---------------- direct conv3x3 (pad=1) implicit GEMM ----------------
// in  [B][256][100][152], wt [2304][256] (transposed), out same layout.
// block: 256 thr; tile 32 px x 256 co; thread: 8 co x 4 px.
__global__ __launch_bounds__(256) void conv3x3_kernel(
    const float* __restrict__ in, const float* __restrict__ wt,
    const float* __restrict__ bias, float* __restrict__ out, int relu)
{
    __shared__ float w_lds[36 * 256];
    __shared__ float in_lds[4][6][12];

    const int tid = threadIdx.x;
    const int x0 = blockIdx.x * TW;
    const int y0 = blockIdx.y * TH;
    const int b  = blockIdx.z;

    const int og = tid >> 3, pg = tid & 7;
    const int co0 = og * 8;
    const int prow = pg >> 1, pcol0 = (pg & 1) * 4;

    float acc[8][4];
#pragma unroll
    for (int j = 0; j < 8; j++)
#pragma unroll
        for (int i = 0; i < 4; i++) acc[j][i] = 0.f;

    for (int ci0 = 0; ci0 < C_; ci0 += 4) {
        // stage input halo tile: 4ci x 6row x 10col
        if (tid < 240) {
            int ci = tid / 60, r = (tid % 60) / 10, c = tid % 10;
            int yy = y0 - 1 + r, xx = x0 - 1 + c;
            float v = 0.f;
            if (yy >= 0 && yy < H_ && xx >= 0 && xx < W_)
                v = in[((size_t)(b * C_ + ci0 + ci) * H_ + yy) * W_ + xx];
            in_lds[ci][r][c] = v;
        }
        // stage weights: rows ci0*9 .. +35, 36*256 floats, coalesced float4
        const float4* wsrc = (const float4*)(wt + (size_t)ci0 * 9 * C_);
        float4* wdst = (float4*)w_lds;
#pragma unroll
        for (int j = 0; j < 9; j++) wdst[j * 256 + tid] = wsrc[j * 256 + tid];
        __syncthreads();

#pragma unroll
        for (int ci = 0; ci < 4; ci++)
#pragma unroll
            for (int kk = 0; kk < 9; kk++) {
                const int ky = kk / 3, kx = kk % 3;
                float v[4];
#pragma unroll
                for (int i = 0; i < 4; i++) v[i] = in_lds[ci][prow + ky][pcol0 + i + kx];
                const float* wr = &w_lds[(ci * 9 + kk) * 256 + co0];
                float4 wa = *(const float4*)wr;
                float4 wb = *(const float4*)(wr + 4);
#pragma unroll
                for (int i = 0; i < 4; i++) {
                    acc[0][i] = fmaf(wa.x, v[i], acc[0][i]);
                    acc[1][i] = fmaf(wa.y, v[i], acc[1][i]);
                    acc[2][i] = fmaf(wa.z, v[i], acc[2][i]);
                    acc[3][i] = fmaf(wa.w, v[i], acc[3][i]);
                    acc[4][i] = fmaf(wb.x, v[i], acc[4][i]);
                    acc[5][i] = fmaf(wb.y, v[i], acc[5][i]);
                    acc[6][i] = fmaf(wb.z, v[i], acc[6][i]);
                    acc[7][i] = fmaf(wb.w, v[i], acc[7][i]);
                }
            }
        __syncthreads();
    }

    const int y = y0 + prow, xb = x0 + pcol0;
#pragma unroll
    for (int j = 0; j < 8; j++) {
        int co = co0 + j;
        float bv = bias[co];
        float4 o;
        o.x = acc[j][0] + bv; o.y = acc[j][1] + bv;
        o.z = acc[j][2] + bv; o.w = acc[j][3] + bv;
        if (relu) {
            o.x = fmaxf(o.x, 0.f); o.y = fmaxf(o.y, 0.f);
            o.z = fmaxf(o.z, 0.f); o.w = fmaxf(o.w, 0.f);
        }
        *(float4*)(out + ((size_t)(b * C_ + co) * H_ + y) * W_ + xb) = o;
    }
}

// ---------------- GroupNorm stats: one block per (b,g) ----------------
__global__ __launch_bounds__(256) void gn_stats_kernel(
    const float* __restrict__ x, float* __restrict__ stats)
{
    __shared__ float r1[256], r2[256];
    const int tid = threadIdx.x;
    const int b = blockIdx.x >> 5, g = blockIdx.x & 31;
    const float4* p = (const float4*)(x + (size_t)(b * C_ + g * 8) * HW_);
    const int n4 = 8 * HW_ / 4;  // 30400
    float s = 0.f, ss = 0.f;
    for (int i = tid; i < n4; i += 256) {
        float4 v = p[i];
        s  += v.x + v.y + v.z + v.w;
        ss += v.x * v.x + v.y * v.y + v.z * v.z + v.w * v.w;
    }
    r1[tid] = s; r2[tid] = ss;
    __syncthreads();
    for (int off = 128; off > 0; off >>= 1) {
        if (tid < off) { r1[tid] += r1[tid + off]; r2[tid] += r2[tid + off]; }
        __syncthreads();
    }
    if (tid == 0) {
        float inv_n = 1.f / (8.f * HW_);
        float mean = r1[0] * inv_n;
        float var  = r2[0] * inv_n - mean * mean;
        stats[blockIdx.x * 2]     = mean;
        stats[blockIdx.x * 2 + 1] = 1.f / sqrtf(var + 1e-5f);
    }
}

// ---------------- GroupNorm apply + ReLU, in place ----------------
__global__ __launch_bounds__(256) void gn_apply_kernel(
    float* __restrict__ buf, const float* __restrict__ stats,
    const float* __restrict__ gamma, const float* __restrict__ beta)
{
    int i = blockIdx.x * 256 + threadIdx.x;
    const int n4 = B_ * C_ * HW_ / 4;  // 3,891,200
    if (i >= n4) return;
    float4 v = ((const float4*)buf)[i];
    int e = i / (HW_ / 4);   // b*256 + c
    int c = e & 255;
    int b = e >> 8;
    int g = c >> 3;
    float mean = stats[(b * GN_G + g) * 2];
    float rs   = stats[(b * GN_G + g) * 2 + 1];
    float ga = gamma[c] * rs;
    float be = beta[c] - mean * ga;
    v.x = fmaxf(v.x * ga + be, 0.f);
    v.y = fmaxf(v.y * ga + be, 0.f);
    v.z = fmaxf(v.z * ga + be, 0.f);
    v.w = fmaxf(v.w * ga + be, 0.f);
    ((float4*)buf)[i] = v;
}

// ---------------- NCHW -> NHWC transpose ----------------
__global__ __launch_bounds__(256) void nchw_to_nhwc_kernel(
    const float* __restrict__ in, float* __restrict__ out)
{
    __shared__ float t[64][65];
    const int lane = threadIdx.x & 63, grp = threadIdx.x >> 6;
    const int p0 = blockIdx.x * 64;
    const int c0 = blockIdx.y * 64;
    const int b  = blockIdx.z;
#pragma unroll
    for (int j = 0; j < 16; j++) {
        int c = c0 + j * 4 + grp;
        int p = p0 + lane;
        float v = (p < HW_) ? in[((size_t)(b * C_ + c)) * HW_ + p] : 0.f;
        t[j * 4 + grp][lane] = v;
    }
    __syncthreads();
#pragma unroll
    for (int j = 0; j < 16; j++) {
        int p = p0 + j * 4 + grp;
        int c = c0 + lane;
        if (p < HW_) out[((size_t)b * HW_ + p) * C_ + c] = t[lane][j * 4 + grp];
    }
}

// ---------------- deformable conv 3x3 (+ fused ReLU) ----------------
// feat NHWC [B][H][W][C], pts [B][18][H][W], wt [2304][256], out NCHW [B][256][H][W]
__global__ __launch_bounds__(256) void deform_kernel(
    const float* __restrict__ feat, const float* __restrict__ pts,
    const float* __restrict__ wt, float* __restrict__ out)
{
    __shared__ float w_lds[36 * 256];
    __shared__ float s_lds[4][9][32];
    __shared__ int   p_off[288][4];
    __shared__ float p_wgt[288][4];

    const int tid = threadIdx.x;
    const int x0 = blockIdx.x * TW;
    const int y0 = blockIdx.y * TH;
    const int b  = blockIdx.z;

    // precompute bilinear params per (px, k)
    for (int pr = tid; pr < NPX * 9; pr += 256) {
        int px_id = pr & 31;
        int k     = pr >> 5;
        int py = px_id >> 3, pxx = px_id & 7;
        int y = y0 + py, x = x0 + pxx;
        const float* pb = pts + ((size_t)b * 18 + 2 * k) * HW_ + y * W_ + x;
        float oy = pb[0], ox = pb[HW_];
        // gradient_mul forward value, base offsets cancel analytically
        float gy = (float)y + (0.1f * oy + 0.9f * oy);
        float gx = (float)x + (0.1f * ox + 0.9f * ox);
        float fy0 = floorf(gy), fx0 = floorf(gx);
        float dy = gy - fy0, dx = gx - fx0;
        int iy0 = (int)fy0, ix0 = (int)fx0;
        float wy[2] = {1.f - dy, dy};
        float wx[2] = {1.f - dx, dx};
#pragma unroll
        for (int cy = 0; cy < 2; cy++)
#pragma unroll
            for (int cx = 0; cx < 2; cx++) {
                int yy = iy0 + cy, xx = ix0 + cx;
                bool valid = (yy >= 0) && (yy < H_) && (xx >= 0) && (xx < W_);
                int yc = min(max(yy, 0), H_ - 1);
                int xc = min(max(xx, 0), W_ - 1);
                p_off[pr][cy * 2 + cx] = (yc * W_ + xc) * C_;
                p_wgt[pr][cy * 2 + cx] = valid ? wy[cy] * wx[cx] : 0.f;
            }
    }

    float acc[8][4];
#pragma unroll
    for (int j = 0; j < 8; j++)
#pragma unroll
        for (int i = 0; i < 4; i++) acc[j][i] = 0.f;

    const int og = tid >> 3, pg = tid & 7;
    const int co0 = og * 8;
    const int prow = pg >> 1, pcol0 = (pg & 1) * 4;
    const float* featb = feat + (size_t)b * HW_ * C_;

    __syncthreads();

    for (int ci0 = 0; ci0 < C_; ci0 += 4) {
        // stage weights
        const float4* wsrc = (const float4*)(wt + (size_t)ci0 * 9 * C_);
        float4* wdst = (float4*)w_lds;
#pragma unroll
        for (int j = 0; j < 9; j++) wdst[j * 256 + tid] = wsrc[j * 256 + tid];
        // sample 4 channels for all (px,k)
        const float* fb = featb + ci0;
        for (int pr = tid; pr < NPX * 9; pr += 256) {
            int px_id = pr & 31, k = pr >> 5;
            int4  of = *(const int4*)p_off[pr];
            float4 wg = *(const float4*)p_wgt[pr];
            float4 v0 = *(const float4*)(fb + of.x);
            float4 v1 = *(const float4*)(fb + of.y);
            float4 v2 = *(const float4*)(fb + of.z);
            float4 v3 = *(const float4*)(fb + of.w);
            s_lds[0][k][px_id] = wg.x * v0.x + wg.y * v1.x + wg.z * v2.x + wg.w * v3.x;
            s_lds[1][k][px_id] = wg.x * v0.y + wg.y * v1.y + wg.z * v2.y + wg.w * v3.y;
            s_lds[2][k][px_id] = wg.x * v0.z + wg.y * v1.z + wg.z * v2.z + wg.w * v3.z;
            s_lds[3][k][px_id] = wg.x * v0.w + wg.y * v1.w + wg.z * v2.w + wg.w * v3.w;
        }
        __syncthreads();

#pragma unroll
        for (int ci = 0; ci < 4; ci++)
#pragma unroll
            for (int kk = 0; kk < 9; kk++) {
                float v[4];
#pragma unroll
                for (int i = 0; i < 4; i++) v[i] = s_lds[ci][kk][prow * 8 + pcol0 + i];
                const float* wr = &w_lds[(ci * 9 + kk) * 256 + co0];
                float4 wa = *(const float4*)wr;
                float4 wb = *(const float4*)(wr + 4);
#pragma unroll
                for (int i = 0; i < 4; i++) {
                    acc[0][i] = fmaf(wa.x, v[i], acc[0][i]);
                    acc[1][i] = fmaf(wa.y, v[i], acc[1][i]);
                    acc[2][i] = fmaf(wa.z, v[i], acc[2][i]);
                    acc[3][i] = fmaf(wa.w, v[i], acc[3][i]);
                    acc[4][i] = fmaf(wb.x, v[i], acc[4][i]);
                    acc[5][i] = fmaf(wb.y, v[i], acc[5][i]);
                    acc[6][i] = fmaf(wb.z, v[i], acc[6][i]);
                    acc[7][i] = fmaf(wb.w, v[i], acc[7][i]);
                }
            }
        __syncthreads();
    }

    const int y = y0 + prow, xb = x0 + pcol0;
#pragma unroll
    for (int j = 0; j < 8; j++) {
        int co = co0 + j;
        float4 o;
        o.x = fmaxf(acc[j][0], 0.f);
        o.y = fmaxf(acc[j][1], 0.f);
        o.z = fmaxf(acc[j][2], 0.f);
        o.w = fmaxf(acc[j][3], 0.f);
        *(float4*)(out + ((size_t)(b * C_ + co) * H_ + y) * W_ + xb) = o;
    }
}

// ---------------- 1x1 conv, small O ----------------
// feat NCHW, wt [256][OP] transposed+padded. block: 64 px x 4 o-groups.
template <int NO4>
__global__ __launch_bounds__(256) void conv1x1_kernel(
    const float* __restrict__ feat, const float* __restrict__ wt,
    const float* __restrict__ bias, const float* __restrict__ addsrc,
    float* __restrict__ outp, int O, int OP)
{
    const int tid = threadIdx.x;
    const int px = blockIdx.x * 64 + (tid & 63);
    const int og = tid >> 6;
    const int o0 = og * NO4 * 4;
    const int b = px / HW_;
    const int rem = px - b * HW_;
    const float* f = feat + (size_t)b * C_ * HW_ + rem;

    float4 acc[NO4];
#pragma unroll
    for (int j = 0; j < NO4; j++) acc[j] = make_float4(0.f, 0.f, 0.f, 0.f);

#pragma unroll 4
    for (int c = 0; c < C_; c++) {
        float fv = f[(size_t)c * HW_];
        const float4* wr = (const float4*)(wt + c * OP + o0);
#pragma unroll
        for (int j = 0; j < NO4; j++) {
            float4 w4 = wr[j];
            acc[j].x = fmaf(fv, w4.x, acc[j].x);
            acc[j].y = fmaf(fv, w4.y, acc[j].y);
            acc[j].z = fmaf(fv, w4.z, acc[j].z);
            acc[j].w = fmaf(fv, w4.w, acc[j].w);
        }
    }
#pragma unroll
    for (int j = 0; j < NO4; j++) {
        float vv[4] = {acc[j].x, acc[j].y, acc[j].z, acc[j].w};
#pragma unroll
        for (int q = 0; q < 4; q++) {
            int o = o0 + j * 4 + q;
            if (o < O) {
                float val = vv[q] + bias[o];
                size_t oi = ((size_t)b * O + o) * HW_ + rem;
                if (addsrc) val += addsrc[oi];
                outp[oi] = val;
            }
        }
    }
}

// ---------------- host launch ----------------
extern "C" void kernel_launch(void* const* d_in, const int* in_sizes, int n_in,
                              void* d_out, int out_size, void* d_ws, size_t ws_size,
                              hipStream_t stream)
{
    (void)in_sizes; (void)n_in; (void)out_size; (void)ws_size;

    const float* x           = (const float*)d_in[0];
    const float* cls_w       = (const float*)d_in[1];
    const float* cls_b       = (const float*)d_in[2];
    const float* cls_gn_g    = (const float*)d_in[3];
    const float* cls_gn_b    = (const float*)d_in[4];
    const float* reg_w       = (const float*)d_in[5];
    const float* reg_b       = (const float*)d_in[6];
    const float* reg_gn_g    = (const float*)d_in[7];
    const float* reg_gn_b    = (const float*)d_in[8];
    const float* init_conv_w = (const float*)d_in[9];
    const float* init_conv_b = (const float*)d_in[10];
    const float* init_out_w  = (const float*)d_in[11];
    const float* init_out_b  = (const float*)d_in[12];
    const float* cls_dcn_w   = (const float*)d_in[13];
    const float* cls_out_w   = (const float*)d_in[14];
    const float* cls_out_b   = (const float*)d_in[15];
    const float* ref_dcn_w   = (const float*)d_in[16];
    const float* ref_out_w   = (const float*)d_in[17];
    const float* ref_out_b   = (const float*)d_in[18];

    float* out = (float*)d_out;
    float* ws  = (float*)d_ws;

    const size_t NF = (size_t)B_ * C_ * HW_;   // 7,782,400 floats per big buffer
    float* bufA  = ws;
    float* bufB  = ws + NF;
    float* bufC  = ws + 2 * NF;
    float* bufD  = ws + 3 * NF;
    float* wt    = ws + 4 * NF;                 // 2304*256 = 589,824
    float* wt1   = wt + (size_t)CK * C_;        // 256*80   = 20,480
    float* stats = wt1 + 256 * 80;              // 128

    const dim3 convGrid(W_ / TW, H_ / TH, B_);  // 19 x 25 x 2
    const dim3 twGrid(4, 36);
    const dim3 nhwcGrid((HW_ + 63) / 64, C_ / 64, B_);
    const int  px_blocks = (B_ * HW_) / 64;     // 475
    const int  gn_apply_blocks = (B_ * C_ * HW_ / 4 + 255) / 256;

    auto conv3 = [&](const float* src, float* dst, const float* wsrc,
                     const float* bias, int relu) {
        transpose_w_kernel<<<twGrid, 256, 0, stream>>>(wsrc, wt);
        conv3x3_kernel<<<convGrid, 256, 0, stream>>>(src, wt, bias, dst, relu);
    };
    auto gn = [&](float* buf, const float* g, const float* be) {
        gn_stats_kernel<<<B_ * GN_G, 256, 0, stream>>>(buf, stats);
        gn_apply_kernel<<<gn_apply_blocks, 256, 0, stream>>>(buf, stats, g, be);
    };

    // --- towers ---
    {
        const float* cur = x;
        float* bufs[2] = {bufA, bufB};
        for (int s = 0; s < 3; s++) {
            float* dst = bufs[s & 1];
            conv3(cur, dst, cls_w + (size_t)s * C_ * CK, cls_b + s * C_, 0);
            gn(dst, cls_gn_g + s * C_, cls_gn_b + s * C_);
            cur = dst;
        }
    }  // cls_feat in bufA
    {
        const float* cur = x;
        float* bufs[2] = {bufC, bufD};
        for (int s = 0; s < 3; s++) {
            float* dst = bufs[s & 1];
            conv3(cur, dst, reg_w + (size_t)s * C_ * CK, reg_b + s * C_, 0);
            gn(dst, reg_gn_g + s * C_, reg_gn_b + s * C_);
            cur = dst;
        }
    }  // pts_feat in bufC

    // --- init branch: relu(conv3x3(pts_feat)) -> 1x1 (18) -> d_out[OFF_INIT] ---
    conv3(bufC, bufD, init_conv_w, init_conv_b, 1);
    transpose_w1_kernel<<<C_, 128, 0, stream>>>(init_out_w, wt1, 18, 32);
    conv1x1_kernel<2><<<px_blocks, 256, 0, stream>>>(
        bufD, wt1, init_out_b, nullptr, out + OFF_INIT, 18, 32);

    // --- NHWC copies for sampling ---
    nchw_to_nhwc_kernel<<<nhwcGrid, 256, 0, stream>>>(bufA, bufB);  // cls NHWC
    nchw_to_nhwc_kernel<<<nhwcGrid, 256, 0, stream>>>(bufC, bufD);  // pts NHWC

    // --- cls deform + 1x1 ---
    transpose_w_kernel<<<twGrid, 256, 0, stream>>>(cls_dcn_w, wt);
    deform_kernel<<<convGrid, 256, 0, stream>>>(bufB, out + OFF_INIT, wt, bufA);
    transpose_w1_kernel<<<C_, 128, 0, stream>>>(cls_out_w, wt1, 80, 80);
    conv1x1_kernel<5><<<px_blocks, 256, 0, stream>>>(
        bufA, wt1, cls_out_b, nullptr, out, 80, 80);

    // --- refine deform + 1x1 (+ pts_out_init) ---
    transpose_w_kernel<<<twGrid, 256, 0, stream>>>(ref_dcn_w, wt);
    deform_kernel<<<convGrid, 256, 0, stream>>>(bufD, out + OFF_INIT, wt, bufC);
    transpose_w1_kernel<<<C_, 128, 0, stream>>>(ref_out_w, wt1, 18, 32);
    conv1x1_kernel<2><<<px_blocks, 256, 0, stream>>>(
        bufC, wt1, ref_out_b, out + OFF_INIT, out + OFF_REF, 18, 32);
}

// Round 2
// 2730.036 us; speedup vs baseline: 1.9413x; 1.9413x over previous
//
#include <hip/hip_runtime.h>

// ---------------- problem constants ----------------
constexpr int B_  = 2;
constexpr int C_  = 256;
constexpr int H_  = 100;
constexpr int W_  = 152;
constexpr int HW_ = H_ * W_;          // 15200
constexpr int K9 = 9;
constexpr int CK = C_ * K9;           // 2304

constexpr int OFF_INIT = B_ * 80 * HW_;              // 2,432,000
constexpr int OFF_REF  = OFF_INIT + B_ * 18 * HW_;   // 2,979,200

typedef __attribute__((ext_vector_type(8))) short short8;
typedef __attribute__((ext_vector_type(4))) float f32x4;

__device__ inline unsigned short f2b(float f) {
    union { float f; unsigned u; } x; x.f = f;
    unsigned r = x.u + 0x7fff + ((x.u >> 16) & 1);   // RNE
    return (unsigned short)(r >> 16);
}

// ---------------- NCHW fp32 -> NHWC bf16 (input transform) ----------------
__global__ __launch_bounds__(256) void to_nhwc_b16_kernel(
    const float* __restrict__ in, unsigned short* __restrict__ outb)
{
    __shared__ float t[64][65];
    const int lane = threadIdx.x & 63, grp = threadIdx.x >> 6;
    const int p0 = blockIdx.x * 64;
    const int c0 = blockIdx.y * 64;
    const int b  = blockIdx.z;
#pragma unroll
    for (int j = 0; j < 16; j++) {
        int c = c0 + j * 4 + grp;
        int p = p0 + lane;
        float v = (p < HW_) ? in[((size_t)(b * C_ + c)) * HW_ + p] : 0.f;
        t[j * 4 + grp][lane] = v;
    }
    __syncthreads();
#pragma unroll
    for (int j = 0; j < 16; j++) {
        int p = p0 + j * 4 + grp;
        int c = c0 + lane;
        if (p < HW_) outb[((size_t)b * HW_ + p) * C_ + c] = f2b(t[lane][j * 4 + grp]);
    }
}

// ---------------- weight prep: fp32 [co][ci][3][3] -> bf16 [kk][co][ci] ----------------
__global__ void wprep_kernel(const float* __restrict__ w, unsigned short* __restrict__ wtb)
{
    const int co = blockIdx.x, kk = blockIdx.y, ci = threadIdx.x;
    float v = w[((size_t)co * C_ + ci) * K9 + kk];
    wtb[((size_t)kk * C_ + co) * C_ + ci] = f2b(v);
}

// ---------------- MFMA conv3x3 (pad=1) implicit GEMM ----------------
// act NHWC bf16, wtb [kk][co][ci] bf16, out NHWC fp32.
// block 512 thr = 8 waves (2 Mr x 4 Nc); block tile M=128px(8r x 16c) x N=256.
__global__ __launch_bounds__(512) void conv3x3_mfma_kernel(
    const unsigned short* __restrict__ act, const unsigned short* __restrict__ wtb,
    const float* __restrict__ bias, float* __restrict__ out, int relu)
{
    __shared__ short a_lds[10 * 18 * 40];   // [row][col][ci(32 pad 40)]

    const int tid  = threadIdx.x;
    const int lane = tid & 63, wid = tid >> 6;
    const int wr = wid >> 2, wc = wid & 3;
    const int l15 = lane & 15, lq = lane >> 4;
    const int x0 = blockIdx.x * 16, y0 = blockIdx.y * 8, b = blockIdx.z;

    f32x4 acc[4][4];
#pragma unroll
    for (int mf = 0; mf < 4; mf++)
#pragma unroll
        for (int nf = 0; nf < 4; nf++) acc[mf][nf] = (f32x4){0.f, 0.f, 0.f, 0.f};

    for (int ci0 = 0; ci0 < C_; ci0 += 32) {
        // stage halo tile: 10 rows x 18 cols x 32 ci (bf16), as 16B chunks
        for (int i = tid; i < 720; i += 512) {
            int q = i & 3, px = i >> 2;
            int row = px / 18, col = px - row * 18;
            int y = y0 - 1 + row, x = x0 - 1 + col;
            int4 v = make_int4(0, 0, 0, 0);
            if (y >= 0 && y < H_ && x >= 0 && x < W_)
                v = *(const int4*)(act + ((size_t)(b * HW_ + y * W_ + x) * C_ + ci0 + q * 8));
            *(int4*)(a_lds + px * 40 + q * 8) = v;
        }
        __syncthreads();

#pragma unroll
        for (int kk = 0; kk < 9; kk++) {
            const int ky = kk / 3, kx = kk % 3;
            short8 af[4];
#pragma unroll
            for (int mf = 0; mf < 4; mf++) {
                int row = wr * 4 + mf + ky, col = l15 + kx;
                af[mf] = *(const short8*)(a_lds + (row * 18 + col) * 40 + lq * 8);
            }
#pragma unroll
            for (int nf = 0; nf < 4; nf++) {
                int co = wc * 64 + nf * 16 + l15;
                short8 bf = *(const short8*)(wtb + ((size_t)(kk * C_ + co)) * C_ + ci0 + lq * 8);
#pragma unroll
                for (int mf = 0; mf < 4; mf++)
                    acc[mf][nf] = __builtin_amdgcn_mfma_f32_16x16x32_bf16(
                        af[mf], bf, acc[mf][nf], 0, 0, 0);
            }
        }
        __syncthreads();
    }

    // epilogue: D row=(lane>>4)*4+reg -> x offset; col=lane&15 -> co
#pragma unroll
    for (int nf = 0; nf < 4; nf++) {
        int co = wc * 64 + nf * 16 + l15;
        float bv = bias[co];
#pragma unroll
        for (int mf = 0; mf < 4; mf++) {
            int y = y0 + wr * 4 + mf;
            if (y >= H_) continue;
#pragma unroll
            for (int r = 0; r < 4; r++) {
                int x = x0 + lq * 4 + r;
                if (x >= W_) continue;
                float v = acc[mf][nf][r] + bv;
                if (relu) v = fmaxf(v, 0.f);
                out[((size_t)(b * HW_ + y * W_ + x)) * C_ + co] = v;
            }
        }
    }
}

// ---------------- GN stats (NHWC fp32): partial sums + atomics ----------------
__global__ void zero_stats_kernel(float* __restrict__ stats)
{
    if (threadIdx.x < 128) stats[threadIdx.x] = 0.f;
}

__global__ __launch_bounds__(256) void gn_stats_part_kernel(
    const float* __restrict__ src, float* __restrict__ stats)
{
    __shared__ float r1[256], r2[256];
    const int tid = threadIdx.x;
    const int bg = blockIdx.x >> 3, sl = blockIdx.x & 7;   // 64 groups x 8 slices
    const int b = bg >> 5, g = bg & 31;
    const float* base = src + (size_t)b * HW_ * C_ + g * 8;
    float s = 0.f, ss = 0.f;
    const int p_end = (sl + 1) * 1900;
    for (int p = sl * 1900 + tid; p < p_end; p += 256) {
        float4 v0 = *(const float4*)(base + (size_t)p * C_);
        float4 v1 = *(const float4*)(base + (size_t)p * C_ + 4);
        s  += v0.x + v0.y + v0.z + v0.w + v1.x + v1.y + v1.z + v1.w;
        ss += v0.x * v0.x + v0.y * v0.y + v0.z * v0.z + v0.w * v0.w
            + v1.x * v1.x + v1.y * v1.y + v1.z * v1.z + v1.w * v1.w;
    }
    r1[tid] = s; r2[tid] = ss;
    __syncthreads();
    for (int off = 128; off > 0; off >>= 1) {
        if (tid < off) { r1[tid] += r1[tid + off]; r2[tid] += r2[tid + off]; }
        __syncthreads();
    }
    if (tid == 0) {
        atomicAdd(&stats[bg * 2],     r1[0]);
        atomicAdd(&stats[bg * 2 + 1], r2[0]);
    }
}

// ---------------- GN apply + ReLU: fp32 NHWC -> bf16 NHWC (+opt fp32 NHWC) ----------------
__global__ __launch_bounds__(256) void gn_apply_kernel(
    const float* __restrict__ src, unsigned short* __restrict__ dstb,
    float* __restrict__ dstf, const float* __restrict__ stats,
    const float* __restrict__ gamma, const float* __restrict__ beta)
{
    const int i = blockIdx.x * 256 + threadIdx.x;   // chunk of 8 channels
    if (i >= B_ * HW_ * 32) return;
    const int c8 = i & 31;            // == group id
    const int pxb = i >> 5;
    const int b = (pxb >= HW_) ? 1 : 0;
    const float inv_n = 1.f / (8.f * HW_);
    float s1 = stats[(b * 32 + c8) * 2];
    float s2 = stats[(b * 32 + c8) * 2 + 1];
    float mean = s1 * inv_n;
    float var  = s2 * inv_n - mean * mean;
    float rs = rsqrtf(var + 1e-5f);

    float4 v0 = *(const float4*)(src + (size_t)i * 8);
    float4 v1 = *(const float4*)(src + (size_t)i * 8 + 4);
    float vin[8] = {v0.x, v0.y, v0.z, v0.w, v1.x, v1.y, v1.z, v1.w};
    float vo[8];
#pragma unroll
    for (int j = 0; j < 8; j++) {
        int c = c8 * 8 + j;
        float ga = gamma[c] * rs;
        float be = beta[c] - mean * ga;
        vo[j] = fmaxf(fmaf(vin[j], ga, be), 0.f);
    }
    unsigned pk[4];
#pragma unroll
    for (int j = 0; j < 4; j++)
        pk[j] = (unsigned)f2b(vo[2 * j]) | ((unsigned)f2b(vo[2 * j + 1]) << 16);
    *(int4*)(dstb + (size_t)i * 8) = make_int4(pk[0], pk[1], pk[2], pk[3]);
    if (dstf) {
        *(float4*)(dstf + (size_t)i * 8)     = make_float4(vo[0], vo[1], vo[2], vo[3]);
        *(float4*)(dstf + (size_t)i * 8 + 4) = make_float4(vo[4], vo[5], vo[6], vo[7]);
    }
}

// ---------------- weight transpose for deform: [256][2304] -> [2304][256] fp32 ----------------
__global__ __launch_bounds__(256) void transpose_w_kernel(
    const float* __restrict__ w, float* __restrict__ wt)
{
    __shared__ float t[64][65];
    const int lane = threadIdx.x & 63, grp = threadIdx.x >> 6;
    const int o0 = blockIdx.x * 64;
    const int k0 = blockIdx.y * 64;
#pragma unroll
    for (int j = 0; j < 16; j++) {
        int o = o0 + j * 4 + grp;
        t[j * 4 + grp][lane] = w[(size_t)o * CK + k0 + lane];
    }
    __syncthreads();
#pragma unroll
    for (int j = 0; j < 16; j++) {
        int k = k0 + j * 4 + grp;
        wt[(size_t)k * C_ + o0 + lane] = t[lane][j * 4 + grp];
    }
}

// ---------------- deformable conv 3x3 (+ fused ReLU), out NHWC fp32 ----------------
// feat NHWC fp32, pts [B][18][H][W] fp32 (NCHW), wt [2304][256] fp32
constexpr int DTH = 4, DTW = 8;
constexpr int DNPX = DTH * DTW;   // 32

__global__ __launch_bounds__(256) void deform_kernel(
    const float* __restrict__ feat, const float* __restrict__ pts,
    const float* __restrict__ wt, float* __restrict__ out)
{
    __shared__ float w_lds[36 * 256];
    __shared__ float s_lds[4][9][32];
    __shared__ int   p_off[288][4];
    __shared__ float p_wgt[288][4];

    const int tid = threadIdx.x;
    const int x0 = blockIdx.x * DTW;
    const int y0 = blockIdx.y * DTH;
    const int b  = blockIdx.z;

    for (int pr = tid; pr < DNPX * 9; pr += 256) {
        int px_id = pr & 31;
        int k     = pr >> 5;
        int py = px_id >> 3, pxx = px_id & 7;
        int y = y0 + py, x = x0 + pxx;
        const float* pb = pts + ((size_t)b * 18 + 2 * k) * HW_ + y * W_ + x;
        float oy = pb[0], ox = pb[HW_];
        float gy = (float)y + oy;
        float gx = (float)x + ox;
        float fy0 = floorf(gy), fx0 = floorf(gx);
        float dy = gy - fy0, dx = gx - fx0;
        int iy0 = (int)fy0, ix0 = (int)fx0;
        float wy[2] = {1.f - dy, dy};
        float wx[2] = {1.f - dx, dx};
#pragma unroll
        for (int cy = 0; cy < 2; cy++)
#pragma unroll
            for (int cx = 0; cx < 2; cx++) {
                int yy = iy0 + cy, xx = ix0 + cx;
                bool valid = (yy >= 0) && (yy < H_) && (xx >= 0) && (xx < W_);
                int yc = min(max(yy, 0), H_ - 1);
                int xc = min(max(xx, 0), W_ - 1);
                p_off[pr][cy * 2 + cx] = (yc * W_ + xc) * C_;
                p_wgt[pr][cy * 2 + cx] = valid ? wy[cy] * wx[cx] : 0.f;
            }
    }

    float acc[8][4];
#pragma unroll
    for (int j = 0; j < 8; j++)
#pragma unroll
        for (int i = 0; i < 4; i++) acc[j][i] = 0.f;

    const int og = tid >> 3, pg = tid & 7;
    const int co0 = og * 8;
    const int prow = pg >> 1, pcol0 = (pg & 1) * 4;
    const float* featb = feat + (size_t)b * HW_ * C_;

    __syncthreads();

    for (int ci0 = 0; ci0 < C_; ci0 += 4) {
        const float4* wsrc = (const float4*)(wt + (size_t)ci0 * 9 * C_);
        float4* wdst = (float4*)w_lds;
#pragma unroll
        for (int j = 0; j < 9; j++) wdst[j * 256 + tid] = wsrc[j * 256 + tid];
        const float* fb = featb + ci0;
        for (int pr = tid; pr < DNPX * 9; pr += 256) {
            int px_id = pr & 31, k = pr >> 5;
            int4  of = *(const int4*)p_off[pr];
            float4 wg = *(const float4*)p_wgt[pr];
            float4 v0 = *(const float4*)(fb + of.x);
            float4 v1 = *(const float4*)(fb + of.y);
            float4 v2 = *(const float4*)(fb + of.z);
            float4 v3 = *(const float4*)(fb + of.w);
            s_lds[0][k][px_id] = wg.x * v0.x + wg.y * v1.x + wg.z * v2.x + wg.w * v3.x;
            s_lds[1][k][px_id] = wg.x * v0.y + wg.y * v1.y + wg.z * v2.y + wg.w * v3.y;
            s_lds[2][k][px_id] = wg.x * v0.z + wg.y * v1.z + wg.z * v2.z + wg.w * v3.z;
            s_lds[3][k][px_id] = wg.x * v0.w + wg.y * v1.w + wg.z * v2.w + wg.w * v3.w;
        }
        __syncthreads();

#pragma unroll
        for (int ci = 0; ci < 4; ci++)
#pragma unroll
            for (int kk = 0; kk < 9; kk++) {
                float v[4];
#pragma unroll
                for (int i = 0; i < 4; i++) v[i] = s_lds[ci][kk][prow * 8 + pcol0 + i];
                const float* wr = &w_lds[(ci * 9 + kk) * 256 + co0];
                float4 wa = *(const float4*)wr;
                float4 wb = *(const float4*)(wr + 4);
#pragma unroll
                for (int i = 0; i < 4; i++) {
                    acc[0][i] = fmaf(wa.x, v[i], acc[0][i]);
                    acc[1][i] = fmaf(wa.y, v[i], acc[1][i]);
                    acc[2][i] = fmaf(wa.z, v[i], acc[2][i]);
                    acc[3][i] = fmaf(wa.w, v[i], acc[3][i]);
                    acc[4][i] = fmaf(wb.x, v[i], acc[4][i]);
                    acc[5][i] = fmaf(wb.y, v[i], acc[5][i]);
                    acc[6][i] = fmaf(wb.z, v[i], acc[6][i]);
                    acc[7][i] = fmaf(wb.w, v[i], acc[7][i]);
                }
            }
        __syncthreads();
    }

    // epilogue -> NHWC fp32 with ReLU
    const int y = y0 + prow, xb = x0 + pcol0;
#pragma unroll
    for (int i = 0; i < 4; i++) {
        float* dst = out + ((size_t)(b * HW_ + y * W_ + xb + i)) * C_ + co0;
        float4 o1, o2;
        o1.x = fmaxf(acc[0][i], 0.f); o1.y = fmaxf(acc[1][i], 0.f);
        o1.z = fmaxf(acc[2][i], 0.f); o1.w = fmaxf(acc[3][i], 0.f);
        o2.x = fmaxf(acc[4][i], 0.f); o2.y = fmaxf(acc[5][i], 0.f);
        o2.z = fmaxf(acc[6][i], 0.f); o2.w = fmaxf(acc[7][i], 0.f);
        *(float4*)dst = o1;
        *(float4*)(dst + 4) = o2;
    }
}

// ---------------- 1x1 conv from NHWC fp32 feat, out NCHW fp32 ----------------
template <int NOg>
__global__ __launch_bounds__(256) void conv1x1_kernel(
    const float* __restrict__ feat, const float* __restrict__ w,
    const float* __restrict__ bias, const float* __restrict__ addsrc,
    float* __restrict__ outp, int O)
{
    const int lane = threadIdx.x & 63, og = threadIdx.x >> 6;
    const int px = blockIdx.x * 64 + lane;       // < 30400 exact
    const int b = (px >= HW_) ? 1 : 0;
    const int rem = px - b * HW_;
    const float4* f = (const float4*)(feat + (size_t)px * C_);

    float acc[NOg];
#pragma unroll
    for (int j = 0; j < NOg; j++) acc[j] = 0.f;

    for (int c4 = 0; c4 < 64; c4++) {
        float4 v = f[c4];
#pragma unroll
        for (int j = 0; j < NOg; j++) {
            int o = og * NOg + j;
            if (o < O) {
                float4 w4 = ((const float4*)w)[o * 64 + c4];
                acc[j] = fmaf(v.x, w4.x, acc[j]);
                acc[j] = fmaf(v.y, w4.y, acc[j]);
                acc[j] = fmaf(v.z, w4.z, acc[j]);
                acc[j] = fmaf(v.w, w4.w, acc[j]);
            }
        }
    }
#pragma unroll
    for (int j = 0; j < NOg; j++) {
        int o = og * NOg + j;
        if (o < O) {
            float val = acc[j] + bias[o];
            size_t oi = ((size_t)(b * O + o)) * HW_ + rem;
            if (addsrc) val += addsrc[oi];
            outp[oi] = val;
        }
    }
}

// ---------------- host launch ----------------
extern "C" void kernel_launch(void* const* d_in, const int* in_sizes, int n_in,
                              void* d_out, int out_size, void* d_ws, size_t ws_size,
                              hipStream_t stream)
{
    (void)in_sizes; (void)n_in; (void)out_size; (void)ws_size;

    const float* x           = (const float*)d_in[0];
    const float* cls_w       = (const float*)d_in[1];
    const float* cls_b       = (const float*)d_in[2];
    const float* cls_gn_g    = (const float*)d_in[3];
    const float* cls_gn_b    = (const float*)d_in[4];
    const float* reg_w       = (const float*)d_in[5];
    const float* reg_b       = (const float*)d_in[6];
    const float* reg_gn_g    = (const float*)d_in[7];
    const float* reg_gn_b    = (const float*)d_in[8];
    const float* init_conv_w = (const float*)d_in[9];
    const float* init_conv_b = (const float*)d_in[10];
    const float* init_out_w  = (const float*)d_in[11];
    const float* init_out_b  = (const float*)d_in[12];
    const float* cls_dcn_w   = (const float*)d_in[13];
    const float* cls_out_w   = (const float*)d_in[14];
    const float* cls_out_b   = (const float*)d_in[15];
    const float* ref_dcn_w   = (const float*)d_in[16];
    const float* ref_out_w   = (const float*)d_in[17];
    const float* ref_out_b   = (const float*)d_in[18];

    float* out = (float*)d_out;
    float* ws  = (float*)d_ws;

    const size_t NF = (size_t)B_ * C_ * HW_;   // 7,782,400
    float* cls32 = ws;
    float* pts32 = ws + NF;
    float* tmp32 = ws + 2 * NF;
    unsigned short* xb16 = (unsigned short*)(ws + 3 * NF);
    unsigned short* act0 = xb16 + NF;
    unsigned short* act1 = act0 + NF;
    unsigned short* wtb  = act1 + NF;                       // 589,824 bf16
    float* wt32  = ws + 3 * NF + (3 * NF + 589824) / 2;     // 589,824 fp32
    float* stats = wt32 + 589824;                           // 128

    const dim3 mfmaGrid(10, 13, 2);        // x-tiles of 16, y-tiles of 8
    const dim3 wprepGrid(C_, 9);
    const dim3 nhwcGrid((HW_ + 63) / 64, C_ / 64, B_);
    const dim3 deformGrid(W_ / DTW, H_ / DTH, B_);
    const dim3 twGrid(4, 36);
    const int  px_blocks = (B_ * HW_) / 64;          // 475
    const int  gn_apply_blocks = (B_ * HW_ * 32) / 256;   // 3800

    auto conv3 = [&](const unsigned short* src, float* dst, const float* wsrc,
                     const float* bias, int relu) {
        wprep_kernel<<<wprepGrid, 256, 0, stream>>>(wsrc, wtb);
        conv3x3_mfma_kernel<<<mfmaGrid, 512, 0, stream>>>(src, wtb, bias, dst, relu);
    };
    auto gn = [&](const float* src, unsigned short* dstb, float* dstf,
                  const float* g, const float* be) {
        zero_stats_kernel<<<1, 128, 0, stream>>>(stats);
        gn_stats_part_kernel<<<512, 256, 0, stream>>>(src, stats);
        gn_apply_kernel<<<gn_apply_blocks, 256, 0, stream>>>(src, dstb, dstf, stats, g, be);
    };

    // input -> NHWC bf16
    to_nhwc_b16_kernel<<<nhwcGrid, 256, 0, stream>>>(x, xb16);

    // --- cls tower ---
    conv3(xb16, tmp32, cls_w,              cls_b,       0);
    gn(tmp32, act0, nullptr, cls_gn_g,       cls_gn_b);
    conv3(act0, tmp32, cls_w + 1 * (size_t)C_ * CK, cls_b + C_, 0);
    gn(tmp32, act1, nullptr, cls_gn_g + C_,  cls_gn_b + C_);
    conv3(act1, tmp32, cls_w + 2 * (size_t)C_ * CK, cls_b + 2 * C_, 0);
    gn(tmp32, act0, cls32,   cls_gn_g + 2 * C_, cls_gn_b + 2 * C_);

    // --- pts tower ---
    conv3(xb16, tmp32, reg_w,              reg_b,       0);
    gn(tmp32, act1, nullptr, reg_gn_g,       reg_gn_b);
    conv3(act1, tmp32, reg_w + 1 * (size_t)C_ * CK, reg_b + C_, 0);
    gn(tmp32, act0, nullptr, reg_gn_g + C_,  reg_gn_b + C_);
    conv3(act0, tmp32, reg_w + 2 * (size_t)C_ * CK, reg_b + 2 * C_, 0);
    gn(tmp32, act1, pts32,   reg_gn_g + 2 * C_, reg_gn_b + 2 * C_);
    // pts final bf16 in act1

    // --- init branch ---
    conv3(act1, tmp32, init_conv_w, init_conv_b, 1);
    conv1x1_kernel<5><<<px_blocks, 256, 0, stream>>>(
        tmp32, init_out_w, init_out_b, nullptr, out + OFF_INIT, 18);

    // --- cls deform + 1x1 ---
    transpose_w_kernel<<<twGrid, 256, 0, stream>>>(cls_dcn_w, wt32);
    deform_kernel<<<deformGrid, 256, 0, stream>>>(cls32, out + OFF_INIT, wt32, tmp32);
    conv1x1_kernel<20><<<px_blocks, 256, 0, stream>>>(
        tmp32, cls_out_w, cls_out_b, nullptr, out, 80);

    // --- refine deform + 1x1 (+ pts_out_init) ---
    transpose_w_kernel<<<twGrid, 256, 0, stream>>>(ref_dcn_w, wt32);
    deform_kernel<<<deformGrid, 256, 0, stream>>>(pts32, out + OFF_INIT, wt32, tmp32);
    conv1x1_kernel<5><<<px_blocks, 256, 0, stream>>>(
        tmp32, ref_out_w, ref_out_b, out + OFF_INIT, out + OFF_REF, 18);
}

// Round 3
// 1743.039 us; speedup vs baseline: 3.0405x; 1.5663x over previous
//
#include <hip/hip_runtime.h>

// ---------------- problem constants ----------------
constexpr int B_  = 2;
constexpr int C_  = 256;
constexpr int H_  = 100;
constexpr int W_  = 152;
constexpr int HW_ = H_ * W_;          // 15200
constexpr int K9 = 9;
constexpr int CK = C_ * K9;           // 2304

constexpr int OFF_INIT = B_ * 80 * HW_;              // 2,432,000
constexpr int OFF_REF  = OFF_INIT + B_ * 18 * HW_;   // 2,979,200

typedef __attribute__((ext_vector_type(8))) short short8;
typedef __attribute__((ext_vector_type(4))) float f32x4;

__device__ inline unsigned short f2b(float f) {
    union { float f; unsigned u; } x; x.f = f;
    unsigned r = x.u + 0x7fff + ((x.u >> 16) & 1);   // RNE
    return (unsigned short)(r >> 16);
}
__device__ inline float b2f(unsigned short b) {
    union { unsigned u; float f; } x; x.u = ((unsigned)b) << 16; return x.f;
}

// ---------------- NCHW fp32 -> NHWC bf16 (input transform) ----------------
__global__ __launch_bounds__(256) void to_nhwc_b16_kernel(
    const float* __restrict__ in, unsigned short* __restrict__ outb)
{
    __shared__ float t[64][65];
    const int lane = threadIdx.x & 63, grp = threadIdx.x >> 6;
    const int p0 = blockIdx.x * 64;
    const int c0 = blockIdx.y * 64;
    const int b  = blockIdx.z;
#pragma unroll
    for (int j = 0; j < 16; j++) {
        int c = c0 + j * 4 + grp;
        int p = p0 + lane;
        float v = (p < HW_) ? in[((size_t)(b * C_ + c)) * HW_ + p] : 0.f;
        t[j * 4 + grp][lane] = v;
    }
    __syncthreads();
#pragma unroll
    for (int j = 0; j < 16; j++) {
        int p = p0 + j * 4 + grp;
        int c = c0 + lane;
        if (p < HW_) outb[((size_t)b * HW_ + p) * C_ + c] = f2b(t[lane][j * 4 + grp]);
    }
}

// ---------------- weight prep: fp32 [co][ci][3][3] -> bf16 [kk][co][ci] ----------------
__global__ void wprep_kernel(const float* __restrict__ w, unsigned short* __restrict__ wtb)
{
    const int co = blockIdx.x, kk = blockIdx.y, ci = threadIdx.x;
    float v = w[((size_t)co * C_ + ci) * K9 + kk];
    wtb[((size_t)kk * C_ + co) * C_ + ci] = f2b(v);
}

// ---------------- MFMA conv3x3 (pad=1) implicit GEMM ----------------
__global__ __launch_bounds__(512) void conv3x3_mfma_kernel(
    const unsigned short* __restrict__ act, const unsigned short* __restrict__ wtb,
    const float* __restrict__ bias, float* __restrict__ out, int relu)
{
    __shared__ short a_lds[10 * 18 * 40];   // [row][col][ci(32 pad 40)]

    const int tid  = threadIdx.x;
    const int lane = tid & 63, wid = tid >> 6;
    const int wr = wid >> 2, wc = wid & 3;
    const int l15 = lane & 15, lq = lane >> 4;
    const int x0 = blockIdx.x * 16, y0 = blockIdx.y * 8, b = blockIdx.z;

    f32x4 acc[4][4];
#pragma unroll
    for (int mf = 0; mf < 4; mf++)
#pragma unroll
        for (int nf = 0; nf < 4; nf++) acc[mf][nf] = (f32x4){0.f, 0.f, 0.f, 0.f};

    for (int ci0 = 0; ci0 < C_; ci0 += 32) {
        for (int i = tid; i < 720; i += 512) {
            int q = i & 3, px = i >> 2;
            int row = px / 18, col = px - row * 18;
            int y = y0 - 1 + row, x = x0 - 1 + col;
            int4 v = make_int4(0, 0, 0, 0);
            if (y >= 0 && y < H_ && x >= 0 && x < W_)
                v = *(const int4*)(act + ((size_t)(b * HW_ + y * W_ + x) * C_ + ci0 + q * 8));
            *(int4*)(a_lds + px * 40 + q * 8) = v;
        }
        __syncthreads();

#pragma unroll
        for (int kk = 0; kk < 9; kk++) {
            const int ky = kk / 3, kx = kk % 3;
            short8 af[4];
#pragma unroll
            for (int mf = 0; mf < 4; mf++) {
                int row = wr * 4 + mf + ky, col = l15 + kx;
                af[mf] = *(const short8*)(a_lds + (row * 18 + col) * 40 + lq * 8);
            }
#pragma unroll
            for (int nf = 0; nf < 4; nf++) {
                int co = wc * 64 + nf * 16 + l15;
                short8 bf = *(const short8*)(wtb + ((size_t)(kk * C_ + co)) * C_ + ci0 + lq * 8);
#pragma unroll
                for (int mf = 0; mf < 4; mf++)
                    acc[mf][nf] = __builtin_amdgcn_mfma_f32_16x16x32_bf16(
                        af[mf], bf, acc[mf][nf], 0, 0, 0);
            }
        }
        __syncthreads();
    }

#pragma unroll
    for (int nf = 0; nf < 4; nf++) {
        int co = wc * 64 + nf * 16 + l15;
        float bv = bias[co];
#pragma unroll
        for (int mf = 0; mf < 4; mf++) {
            int y = y0 + wr * 4 + mf;
            if (y >= H_) continue;
#pragma unroll
            for (int r = 0; r < 4; r++) {
                int x = x0 + lq * 4 + r;
                if (x >= W_) continue;
                float v = acc[mf][nf][r] + bv;
                if (relu) v = fmaxf(v, 0.f);
                out[((size_t)(b * HW_ + y * W_ + x)) * C_ + co] = v;
            }
        }
    }
}

// ---------------- GN stats (NHWC fp32): partial sums + atomics ----------------
__global__ void zero_stats_kernel(float* __restrict__ stats)
{
    if (threadIdx.x < 128) stats[threadIdx.x] = 0.f;
}

__global__ __launch_bounds__(256) void gn_stats_part_kernel(
    const float* __restrict__ src, float* __restrict__ stats)
{
    __shared__ float r1[256], r2[256];
    const int tid = threadIdx.x;
    const int bg = blockIdx.x >> 3, sl = blockIdx.x & 7;
    const int b = bg >> 5, g = bg & 31;
    const float* base = src + (size_t)b * HW_ * C_ + g * 8;
    float s = 0.f, ss = 0.f;
    const int p_end = (sl + 1) * 1900;
    for (int p = sl * 1900 + tid; p < p_end; p += 256) {
        float4 v0 = *(const float4*)(base + (size_t)p * C_);
        float4 v1 = *(const float4*)(base + (size_t)p * C_ + 4);
        s  += v0.x + v0.y + v0.z + v0.w + v1.x + v1.y + v1.z + v1.w;
        ss += v0.x * v0.x + v0.y * v0.y + v0.z * v0.z + v0.w * v0.w
            + v1.x * v1.x + v1.y * v1.y + v1.z * v1.z + v1.w * v1.w;
    }
    r1[tid] = s; r2[tid] = ss;
    __syncthreads();
    for (int off = 128; off > 0; off >>= 1) {
        if (tid < off) { r1[tid] += r1[tid + off]; r2[tid] += r2[tid + off]; }
        __syncthreads();
    }
    if (tid == 0) {
        atomicAdd(&stats[bg * 2],     r1[0]);
        atomicAdd(&stats[bg * 2 + 1], r2[0]);
    }
}

// ---------------- GN apply + ReLU: fp32 NHWC -> bf16 NHWC ----------------
__global__ __launch_bounds__(256) void gn_apply_kernel(
    const float* __restrict__ src, unsigned short* __restrict__ dstb,
    const float* __restrict__ stats,
    const float* __restrict__ gamma, const float* __restrict__ beta)
{
    const int i = blockIdx.x * 256 + threadIdx.x;   // chunk of 8 channels
    if (i >= B_ * HW_ * 32) return;
    const int c8 = i & 31;            // == group id
    const int pxb = i >> 5;
    const int b = (pxb >= HW_) ? 1 : 0;
    const float inv_n = 1.f / (8.f * HW_);
    float s1 = stats[(b * 32 + c8) * 2];
    float s2 = stats[(b * 32 + c8) * 2 + 1];
    float mean = s1 * inv_n;
    float var  = s2 * inv_n - mean * mean;
    float rs = rsqrtf(var + 1e-5f);

    float4 v0 = *(const float4*)(src + (size_t)i * 8);
    float4 v1 = *(const float4*)(src + (size_t)i * 8 + 4);
    float vin[8] = {v0.x, v0.y, v0.z, v0.w, v1.x, v1.y, v1.z, v1.w};
    float vo[8];
#pragma unroll
    for (int j = 0; j < 8; j++) {
        int c = c8 * 8 + j;
        float ga = gamma[c] * rs;
        float be = beta[c] - mean * ga;
        vo[j] = fmaxf(fmaf(vin[j], ga, be), 0.f);
    }
    unsigned pk[4];
#pragma unroll
    for (int j = 0; j < 4; j++)
        pk[j] = (unsigned)f2b(vo[2 * j]) | ((unsigned)f2b(vo[2 * j + 1]) << 16);
    *(int4*)(dstb + (size_t)i * 8) = make_int4(pk[0], pk[1], pk[2], pk[3]);
}

// ---------------- MFMA deformable conv 3x3 (+ fused ReLU) ----------------
// feat bf16 NHWC (both images), pts [B][18][HW] fp32, wtb bf16 [kk][co][ci],
// out fp32 NHWC. Tile: M=32 px (linear), N=256 co; 256 thr = 4 waves (wc).
__global__ __launch_bounds__(256) void deform_mfma_kernel(
    const unsigned short* __restrict__ feat, const float* __restrict__ pts,
    const unsigned short* __restrict__ wtb, float* __restrict__ out)
{
    __shared__ __align__(16) short a_lds[32 * 296];  // [px][kk*32+ci], pad 288->296
    __shared__ int   p_off[288][4];
    __shared__ float p_wgt[288][4];

    const int tid = threadIdx.x;
    const int lane = tid & 63, wc = tid >> 6;
    const int l15 = lane & 15, lq = lane >> 4;
    const int px0 = blockIdx.x * 32;

    // ---- bilinear setup: 288 (px,kk) pairs ----
    for (int pr = tid; pr < 288; pr += 256) {
        int px_l = pr / 9, kk = pr - px_l * 9;
        int px = px0 + px_l;
        int b = (px >= HW_) ? 1 : 0;
        int rem = px - b * HW_;
        int y = rem / W_, x = rem - y * W_;
        const float* pb = pts + ((size_t)b * 18 + 2 * kk) * HW_ + rem;
        float oy = pb[0], ox = pb[HW_];
        float gy = (float)y + oy, gx = (float)x + ox;
        float fy0 = floorf(gy), fx0 = floorf(gx);
        float dy = gy - fy0, dx = gx - fx0;
        int iy0 = (int)fy0, ix0 = (int)fx0;
        float wy[2] = {1.f - dy, dy}, wx[2] = {1.f - dx, dx};
#pragma unroll
        for (int cy = 0; cy < 2; cy++)
#pragma unroll
            for (int cx = 0; cx < 2; cx++) {
                int yy = iy0 + cy, xx = ix0 + cx;
                bool valid = (yy >= 0) && (yy < H_) && (xx >= 0) && (xx < W_);
                int yc = min(max(yy, 0), H_ - 1);
                int xc = min(max(xx, 0), W_ - 1);
                p_off[pr][cy * 2 + cx] = (b * HW_ + yc * W_ + xc) * C_;
                p_wgt[pr][cy * 2 + cx] = valid ? wy[cy] * wx[cx] : 0.f;
            }
    }

    f32x4 acc[2][4];
#pragma unroll
    for (int mf = 0; mf < 2; mf++)
#pragma unroll
        for (int nf = 0; nf < 4; nf++) acc[mf][nf] = (f32x4){0.f, 0.f, 0.f, 0.f};

    __syncthreads();

    for (int ci0 = 0; ci0 < C_; ci0 += 32) {
        // ---- sample A-tile: 288 pairs x 4 ci8-chunks ----
        for (int u = tid; u < 1152; u += 256) {
            int q = u & 3, pr = u >> 2;
            int px_l = pr / 9, kk = pr - px_l * 9;
            int4  of = *(const int4*)p_off[pr];
            float4 wg = *(const float4*)p_wgt[pr];
            const unsigned short* fb = feat + ci0 + q * 8;
            short8 v0 = *(const short8*)(fb + of.x);
            short8 v1 = *(const short8*)(fb + of.y);
            short8 v2 = *(const short8*)(fb + of.z);
            short8 v3 = *(const short8*)(fb + of.w);
            unsigned pk[4];
#pragma unroll
            for (int j = 0; j < 4; j++) {
                float r0 = wg.x * b2f((unsigned short)v0[2 * j])
                         + wg.y * b2f((unsigned short)v1[2 * j])
                         + wg.z * b2f((unsigned short)v2[2 * j])
                         + wg.w * b2f((unsigned short)v3[2 * j]);
                float r1 = wg.x * b2f((unsigned short)v0[2 * j + 1])
                         + wg.y * b2f((unsigned short)v1[2 * j + 1])
                         + wg.z * b2f((unsigned short)v2[2 * j + 1])
                         + wg.w * b2f((unsigned short)v3[2 * j + 1]);
                pk[j] = (unsigned)f2b(r0) | ((unsigned)f2b(r1) << 16);
            }
            *(int4*)(a_lds + px_l * 296 + kk * 32 + q * 8) = make_int4(pk[0], pk[1], pk[2], pk[3]);
        }
        __syncthreads();

        // ---- MFMA over 9 taps ----
#pragma unroll
        for (int kk = 0; kk < 9; kk++) {
            short8 af[2];
#pragma unroll
            for (int mf = 0; mf < 2; mf++)
                af[mf] = *(const short8*)(a_lds + (mf * 16 + l15) * 296 + kk * 32 + lq * 8);
#pragma unroll
            for (int nf = 0; nf < 4; nf++) {
                int co = wc * 64 + nf * 16 + l15;
                short8 bf = *(const short8*)(wtb + ((size_t)(kk * C_ + co)) * C_ + ci0 + lq * 8);
#pragma unroll
                for (int mf = 0; mf < 2; mf++)
                    acc[mf][nf] = __builtin_amdgcn_mfma_f32_16x16x32_bf16(
                        af[mf], bf, acc[mf][nf], 0, 0, 0);
            }
        }
        __syncthreads();
    }

    // ---- epilogue: relu -> fp32 NHWC ----
#pragma unroll
    for (int nf = 0; nf < 4; nf++) {
        int co = wc * 64 + nf * 16 + l15;
#pragma unroll
        for (int mf = 0; mf < 2; mf++) {
#pragma unroll
            for (int r = 0; r < 4; r++) {
                int px = px0 + mf * 16 + lq * 4 + r;
                out[(size_t)px * C_ + co] = fmaxf(acc[mf][nf][r], 0.f);
            }
        }
    }
}

// ---------------- 1x1 conv from NHWC fp32 feat, out NCHW fp32 ----------------
template <int NOg>
__global__ __launch_bounds__(256) void conv1x1_kernel(
    const float* __restrict__ feat, const float* __restrict__ w,
    const float* __restrict__ bias, const float* __restrict__ addsrc,
    float* __restrict__ outp, int O)
{
    const int lane = threadIdx.x & 63, og = threadIdx.x >> 6;
    const int px = blockIdx.x * 64 + lane;
    const int b = (px >= HW_) ? 1 : 0;
    const int rem = px - b * HW_;
    const float4* f = (const float4*)(feat + (size_t)px * C_);

    float acc[NOg];
#pragma unroll
    for (int j = 0; j < NOg; j++) acc[j] = 0.f;

    for (int c4 = 0; c4 < 64; c4++) {
        float4 v = f[c4];
#pragma unroll
        for (int j = 0; j < NOg; j++) {
            int o = og * NOg + j;
            if (o < O) {
                float4 w4 = ((const float4*)w)[o * 64 + c4];
                acc[j] = fmaf(v.x, w4.x, acc[j]);
                acc[j] = fmaf(v.y, w4.y, acc[j]);
                acc[j] = fmaf(v.z, w4.z, acc[j]);
                acc[j] = fmaf(v.w, w4.w, acc[j]);
            }
        }
    }
#pragma unroll
    for (int j = 0; j < NOg; j++) {
        int o = og * NOg + j;
        if (o < O) {
            float val = acc[j] + bias[o];
            size_t oi = ((size_t)(b * O + o)) * HW_ + rem;
            if (addsrc) val += addsrc[oi];
            outp[oi] = val;
        }
    }
}

// ---------------- host launch ----------------
extern "C" void kernel_launch(void* const* d_in, const int* in_sizes, int n_in,
                              void* d_out, int out_size, void* d_ws, size_t ws_size,
                              hipStream_t stream)
{
    (void)in_sizes; (void)n_in; (void)out_size; (void)ws_size;

    const float* x           = (const float*)d_in[0];
    const float* cls_w       = (const float*)d_in[1];
    const float* cls_b       = (const float*)d_in[2];
    const float* cls_gn_g    = (const float*)d_in[3];
    const float* cls_gn_b    = (const float*)d_in[4];
    const float* reg_w       = (const float*)d_in[5];
    const float* reg_b       = (const float*)d_in[6];
    const float* reg_gn_g    = (const float*)d_in[7];
    const float* reg_gn_b    = (const float*)d_in[8];
    const float* init_conv_w = (const float*)d_in[9];
    const float* init_conv_b = (const float*)d_in[10];
    const float* init_out_w  = (const float*)d_in[11];
    const float* init_out_b  = (const float*)d_in[12];
    const float* cls_dcn_w   = (const float*)d_in[13];
    const float* cls_out_w   = (const float*)d_in[14];
    const float* cls_out_b   = (const float*)d_in[15];
    const float* ref_dcn_w   = (const float*)d_in[16];
    const float* ref_out_w   = (const float*)d_in[17];
    const float* ref_out_b   = (const float*)d_in[18];

    float* out = (float*)d_out;
    float* ws  = (float*)d_ws;

    const size_t NF = (size_t)B_ * C_ * HW_;   // 7,782,400
    float* tmp32 = ws;
    unsigned short* xb16 = (unsigned short*)(ws + NF);
    unsigned short* bA   = xb16 + NF;
    unsigned short* bB   = bA + NF;
    unsigned short* clsF = bB + NF;
    unsigned short* ptsF = clsF + NF;
    unsigned short* wtb  = ptsF + NF;                  // 589,824 bf16
    float* stats = (float*)(wtb + 589824);             // 128

    const dim3 mfmaGrid(10, 13, 2);
    const dim3 wprepGrid(C_, 9);
    const dim3 nhwcGrid((HW_ + 63) / 64, C_ / 64, B_);
    const int  deformBlocks = (B_ * HW_) / 32;       // 950
    const int  px_blocks = (B_ * HW_) / 64;          // 475
    const int  gn_apply_blocks = (B_ * HW_ * 32) / 256;

    auto conv3 = [&](const unsigned short* src, float* dst, const float* wsrc,
                     const float* bias, int relu) {
        wprep_kernel<<<wprepGrid, 256, 0, stream>>>(wsrc, wtb);
        conv3x3_mfma_kernel<<<mfmaGrid, 512, 0, stream>>>(src, wtb, bias, dst, relu);
    };
    auto gn = [&](const float* src, unsigned short* dstb,
                  const float* g, const float* be) {
        zero_stats_kernel<<<1, 128, 0, stream>>>(stats);
        gn_stats_part_kernel<<<512, 256, 0, stream>>>(src, stats);
        gn_apply_kernel<<<gn_apply_blocks, 256, 0, stream>>>(src, dstb, stats, g, be);
    };

    to_nhwc_b16_kernel<<<nhwcGrid, 256, 0, stream>>>(x, xb16);

    // --- cls tower ---
    conv3(xb16, tmp32, cls_w, cls_b, 0);
    gn(tmp32, bA, cls_gn_g, cls_gn_b);
    conv3(bA, tmp32, cls_w + 1 * (size_t)C_ * CK, cls_b + C_, 0);
    gn(tmp32, bB, cls_gn_g + C_, cls_gn_b + C_);
    conv3(bB, tmp32, cls_w + 2 * (size_t)C_ * CK, cls_b + 2 * C_, 0);
    gn(tmp32, clsF, cls_gn_g + 2 * C_, cls_gn_b + 2 * C_);

    // --- pts tower ---
    conv3(xb16, tmp32, reg_w, reg_b, 0);
    gn(tmp32, bA, reg_gn_g, reg_gn_b);
    conv3(bA, tmp32, reg_w + 1 * (size_t)C_ * CK, reg_b + C_, 0);
    gn(tmp32, bB, reg_gn_g + C_, reg_gn_b + C_);
    conv3(bB, tmp32, reg_w + 2 * (size_t)C_ * CK, reg_b + 2 * C_, 0);
    gn(tmp32, ptsF, reg_gn_g + 2 * C_, reg_gn_b + 2 * C_);

    // --- init branch ---
    conv3(ptsF, tmp32, init_conv_w, init_conv_b, 1);
    conv1x1_kernel<5><<<px_blocks, 256, 0, stream>>>(
        tmp32, init_out_w, init_out_b, nullptr, out + OFF_INIT, 18);

    // --- cls deform + 1x1 ---
    wprep_kernel<<<wprepGrid, 256, 0, stream>>>(cls_dcn_w, wtb);
    deform_mfma_kernel<<<deformBlocks, 256, 0, stream>>>(clsF, out + OFF_INIT, wtb, tmp32);
    conv1x1_kernel<20><<<px_blocks, 256, 0, stream>>>(
        tmp32, cls_out_w, cls_out_b, nullptr, out, 80);

    // --- refine deform + 1x1 (+ pts_out_init) ---
    wprep_kernel<<<wprepGrid, 256, 0, stream>>>(ref_dcn_w, wtb);
    deform_mfma_kernel<<<deformBlocks, 256, 0, stream>>>(ptsF, out + OFF_INIT, wtb, tmp32);
    conv1x1_kernel<5><<<px_blocks, 256, 0, stream>>>(
        tmp32, ref_out_w, ref_out_b, out + OFF_INIT, out + OFF_REF, 18);
}

// Round 4
// 1426.706 us; speedup vs baseline: 3.7147x; 1.2217x over previous
//
#include <hip/hip_runtime.h>

// ---------------- problem constants ----------------
constexpr int B_  = 2;
constexpr int C_  = 256;
constexpr int H_  = 100;
constexpr int W_  = 152;
constexpr int HW_ = H_ * W_;          // 15200
constexpr int K9 = 9;
constexpr int CK = C_ * K9;           // 2304

constexpr int OFF_INIT = B_ * 80 * HW_;              // 2,432,000
constexpr int OFF_REF  = OFF_INIT + B_ * 18 * HW_;   // 2,979,200

typedef __attribute__((ext_vector_type(8))) short short8;
typedef __attribute__((ext_vector_type(4))) float f32x4;

__device__ inline unsigned short f2b(float f) {
    union { float f; unsigned u; } x; x.f = f;
    unsigned r = x.u + 0x7fff + ((x.u >> 16) & 1);   // RNE
    return (unsigned short)(r >> 16);
}
__device__ inline float b2f(unsigned short b) {
    union { unsigned u; float f; } x; x.u = ((unsigned)b) << 16; return x.f;
}

__device__ inline void load_lds16(const void* g, void* l) {
    __builtin_amdgcn_global_load_lds(
        (const __attribute__((address_space(1))) unsigned int*)g,
        (__attribute__((address_space(3))) unsigned int*)l, 16, 0, 0);
}

// ---------------- NCHW fp32 -> NHWC bf16 (input transform) ----------------
__global__ __launch_bounds__(256) void to_nhwc_b16_kernel(
    const float* __restrict__ in, unsigned short* __restrict__ outb)
{
    __shared__ float t[64][65];
    const int lane = threadIdx.x & 63, grp = threadIdx.x >> 6;
    const int p0 = blockIdx.x * 64;
    const int c0 = blockIdx.y * 64;
    const int b  = blockIdx.z;
#pragma unroll
    for (int j = 0; j < 16; j++) {
        int c = c0 + j * 4 + grp;
        int p = p0 + lane;
        float v = (p < HW_) ? in[((size_t)(b * C_ + c)) * HW_ + p] : 0.f;
        t[j * 4 + grp][lane] = v;
    }
    __syncthreads();
#pragma unroll
    for (int j = 0; j < 16; j++) {
        int p = p0 + j * 4 + grp;
        int c = c0 + lane;
        if (p < HW_) outb[((size_t)b * HW_ + p) * C_ + c] = f2b(t[lane][j * 4 + grp]);
    }
}

// ---------------- weight prep: fp32 [co][ci][3][3] -> bf16 [kk][co][ci] ----------------
__global__ void wprep_kernel(const float* __restrict__ w, unsigned short* __restrict__ wtb)
{
    const int co = blockIdx.x, kk = blockIdx.y, ci = threadIdx.x;
    float v = w[((size_t)co * C_ + ci) * K9 + kk];
    wtb[((size_t)kk * C_ + co) * C_ + ci] = f2b(v);
}

// ---------------- zero stats + zero-pad buffer ----------------
__global__ void zero_stats_kernel(float* __restrict__ stats)
{
    if (threadIdx.x < 160) stats[threadIdx.x] = 0.f;
}

// ---------------- MFMA conv3x3 v2: 2-phase dbuf + gload_lds + fused GN stats ----
// act NHWC bf16; wtb [kk][co][ci] bf16; out NHWC fp32.
// Block 256 thr = 4 waves; tile M=64px (4 rows x 16 cols) x N=256 co.
// A-halo per 32-ci chunk: 6 rows x 18 cols -> 432 16B units, padded to 512,
// XOR-swizzled (u ^= (u>>3)&7) with inverse-swizzled global source.
__global__ __launch_bounds__(256) void conv3x3_mfma2_kernel(
    const unsigned short* __restrict__ act, const unsigned short* __restrict__ wtb,
    const float* __restrict__ bias, float* __restrict__ out,
    float* __restrict__ stats, const unsigned short* __restrict__ zbuf, int relu)
{
    __shared__ __align__(16) short a_lds[2][512 * 8];   // 2 x 8KB

    const int tid = threadIdx.x;
    const int lane = tid & 63, wv = tid >> 6;
    const int l15 = lane & 15, lq = lane >> 4;
    const int x0 = blockIdx.x * 16, y0 = blockIdx.y * 4, b = blockIdx.z;

    // ---- per-lane global sources for the 2 staging instructions of this wave ----
    const unsigned short* sbase[2];
    int sstep[2];
#pragma unroll
    for (int j = 0; j < 2; j++) {
        int p = (wv + j * 4) * 64 + lane;          // physical 16B unit
        int v = p ^ ((p >> 3) & 7);                // logical unit (involution)
        const unsigned short* src = zbuf;
        int step = 0;
        if (v < 432) {
            int px = v >> 2, q = v & 3;
            int row = px / 18, col = px - row * 18;
            int y = y0 - 1 + row, x = x0 - 1 + col;
            if (y >= 0 && y < H_ && x >= 0 && x < W_) {
                src = act + ((size_t)(b * HW_ + y * W_ + x) * C_ + q * 8);
                step = 1;
            }
        }
        sbase[j] = src; sstep[j] = step;
    }

    f32x4 acc[4][4];
#pragma unroll
    for (int mf = 0; mf < 4; mf++)
#pragma unroll
        for (int nf = 0; nf < 4; nf++) acc[mf][nf] = (f32x4){0.f, 0.f, 0.f, 0.f};

    auto STAGE = [&](int ci0, int bufi) {
#pragma unroll
        for (int j = 0; j < 2; j++)
            load_lds16(sbase[j] + sstep[j] * ci0,
                       &a_lds[bufi][((wv + j * 4) * 64) * 8]);
    };

    auto COMPUTE = [&](int ci0, int bufi) {
        const short* ab = a_lds[bufi];
#pragma unroll
        for (int kk = 0; kk < 9; kk++) {
            const int ky = kk / 3, kx = kk % 3;
            short8 af[4];
#pragma unroll
            for (int mf = 0; mf < 4; mf++) {
                int lv = ((mf + ky) * 18 + l15 + kx) * 4 + lq;
                int pu = lv ^ ((lv >> 3) & 7);
                af[mf] = *(const short8*)(ab + pu * 8);
            }
#pragma unroll
            for (int nf = 0; nf < 4; nf++) {
                int co = wv * 64 + nf * 16 + l15;
                short8 bf = *(const short8*)(wtb + ((size_t)(kk * C_ + co)) * C_ + ci0 + lq * 8);
#pragma unroll
                for (int mf = 0; mf < 4; mf++)
                    acc[mf][nf] = __builtin_amdgcn_mfma_f32_16x16x32_bf16(
                        af[mf], bf, acc[mf][nf], 0, 0, 0);
            }
        }
    };

    STAGE(0, 0);
    __syncthreads();
    for (int c = 0; c < 8; c++) {
        int cur = c & 1;
        if (c < 7) STAGE((c + 1) * 32, cur ^ 1);
        COMPUTE(c * 32, cur);
        __syncthreads();
    }

    // ---- epilogue: bias (+relu) store NHWC fp32, fused GN partial stats ----
#pragma unroll
    for (int nf = 0; nf < 4; nf++) {
        int co = wv * 64 + nf * 16 + l15;
        float bv = bias[co];
        float s = 0.f, ss = 0.f;
#pragma unroll
        for (int mf = 0; mf < 4; mf++) {
            int y = y0 + mf;
#pragma unroll
            for (int r = 0; r < 4; r++) {
                int x = x0 + lq * 4 + r;
                if (x < W_) {
                    float v = acc[mf][nf][r] + bv;
                    s += v; ss += v * v;
                    out[((size_t)(b * HW_ + y * W_ + x)) * C_ + co] =
                        relu ? fmaxf(v, 0.f) : v;
                }
            }
        }
        if (stats) {
            s  += __shfl_xor(s, 1);  ss += __shfl_xor(ss, 1);
            s  += __shfl_xor(s, 2);  ss += __shfl_xor(ss, 2);
            s  += __shfl_xor(s, 4);  ss += __shfl_xor(ss, 4);
            s  += __shfl_xor(s, 16); ss += __shfl_xor(ss, 16);
            s  += __shfl_xor(s, 32); ss += __shfl_xor(ss, 32);
            if ((lane & 55) == 0) {
                int g = co >> 3;   // wv*8 + nf*2 + (l15>>3)
                atomicAdd(&stats[(b * 32 + g) * 2],     s);
                atomicAdd(&stats[(b * 32 + g) * 2 + 1], ss);
            }
        }
    }
}

// ---------------- GN apply + ReLU: fp32 NHWC -> bf16 NHWC ----------------
__global__ __launch_bounds__(256) void gn_apply_kernel(
    const float* __restrict__ src, unsigned short* __restrict__ dstb,
    const float* __restrict__ stats,
    const float* __restrict__ gamma, const float* __restrict__ beta)
{
    const int i = blockIdx.x * 256 + threadIdx.x;   // chunk of 8 channels
    if (i >= B_ * HW_ * 32) return;
    const int c8 = i & 31;            // == group id
    const int pxb = i >> 5;
    const int b = (pxb >= HW_) ? 1 : 0;
    const float inv_n = 1.f / (8.f * HW_);
    float s1 = stats[(b * 32 + c8) * 2];
    float s2 = stats[(b * 32 + c8) * 2 + 1];
    float mean = s1 * inv_n;
    float var  = s2 * inv_n - mean * mean;
    float rs = rsqrtf(var + 1e-5f);

    float4 v0 = *(const float4*)(src + (size_t)i * 8);
    float4 v1 = *(const float4*)(src + (size_t)i * 8 + 4);
    float vin[8] = {v0.x, v0.y, v0.z, v0.w, v1.x, v1.y, v1.z, v1.w};
    float vo[8];
#pragma unroll
    for (int j = 0; j < 8; j++) {
        int c = c8 * 8 + j;
        float ga = gamma[c] * rs;
        float be = beta[c] - mean * ga;
        vo[j] = fmaxf(fmaf(vin[j], ga, be), 0.f);
    }
    unsigned pk[4];
#pragma unroll
    for (int j = 0; j < 4; j++)
        pk[j] = (unsigned)f2b(vo[2 * j]) | ((unsigned)f2b(vo[2 * j + 1]) << 16);
    *(int4*)(dstb + (size_t)i * 8) = make_int4(pk[0], pk[1], pk[2], pk[3]);
}

// ---------------- MFMA deformable conv 3x3 (+ fused ReLU) ----------------
__global__ __launch_bounds__(256) void deform_mfma_kernel(
    const unsigned short* __restrict__ feat, const float* __restrict__ pts,
    const unsigned short* __restrict__ wtb, float* __restrict__ out)
{
    __shared__ __align__(16) short a_lds[32 * 296];  // [px][kk*32+ci], pad 288->296
    __shared__ int   p_off[288][4];
    __shared__ float p_wgt[288][4];

    const int tid = threadIdx.x;
    const int lane = tid & 63, wc = tid >> 6;
    const int l15 = lane & 15, lq = lane >> 4;
    const int px0 = blockIdx.x * 32;

    for (int pr = tid; pr < 288; pr += 256) {
        int px_l = pr / 9, kk = pr - px_l * 9;
        int px = px0 + px_l;
        int b = (px >= HW_) ? 1 : 0;
        int rem = px - b * HW_;
        int y = rem / W_, x = rem - y * W_;
        const float* pb = pts + ((size_t)b * 18 + 2 * kk) * HW_ + rem;
        float oy = pb[0], ox = pb[HW_];
        float gy = (float)y + oy, gx = (float)x + ox;
        float fy0 = floorf(gy), fx0 = floorf(gx);
        float dy = gy - fy0, dx = gx - fx0;
        int iy0 = (int)fy0, ix0 = (int)fx0;
        float wy[2] = {1.f - dy, dy}, wx[2] = {1.f - dx, dx};
#pragma unroll
        for (int cy = 0; cy < 2; cy++)
#pragma unroll
            for (int cx = 0; cx < 2; cx++) {
                int yy = iy0 + cy, xx = ix0 + cx;
                bool valid = (yy >= 0) && (yy < H_) && (xx >= 0) && (xx < W_);
                int yc = min(max(yy, 0), H_ - 1);
                int xc = min(max(xx, 0), W_ - 1);
                p_off[pr][cy * 2 + cx] = (b * HW_ + yc * W_ + xc) * C_;
                p_wgt[pr][cy * 2 + cx] = valid ? wy[cy] * wx[cx] : 0.f;
            }
    }

    f32x4 acc[2][4];
#pragma unroll
    for (int mf = 0; mf < 2; mf++)
#pragma unroll
        for (int nf = 0; nf < 4; nf++) acc[mf][nf] = (f32x4){0.f, 0.f, 0.f, 0.f};

    __syncthreads();

    for (int ci0 = 0; ci0 < C_; ci0 += 32) {
        for (int u = tid; u < 1152; u += 256) {
            int q = u & 3, pr = u >> 2;
            int px_l = pr / 9, kk = pr - px_l * 9;
            int4  of = *(const int4*)p_off[pr];
            float4 wg = *(const float4*)p_wgt[pr];
            const unsigned short* fb = feat + ci0 + q * 8;
            short8 v0 = *(const short8*)(fb + of.x);
            short8 v1 = *(const short8*)(fb + of.y);
            short8 v2 = *(const short8*)(fb + of.z);
            short8 v3 = *(const short8*)(fb + of.w);
            unsigned pk[4];
#pragma unroll
            for (int j = 0; j < 4; j++) {
                float r0 = wg.x * b2f((unsigned short)v0[2 * j])
                         + wg.y * b2f((unsigned short)v1[2 * j])
                         + wg.z * b2f((unsigned short)v2[2 * j])
                         + wg.w * b2f((unsigned short)v3[2 * j]);
                float r1 = wg.x * b2f((unsigned short)v0[2 * j + 1])
                         + wg.y * b2f((unsigned short)v1[2 * j + 1])
                         + wg.z * b2f((unsigned short)v2[2 * j + 1])
                         + wg.w * b2f((unsigned short)v3[2 * j + 1]);
                pk[j] = (unsigned)f2b(r0) | ((unsigned)f2b(r1) << 16);
            }
            *(int4*)(a_lds + px_l * 296 + kk * 32 + q * 8) = make_int4(pk[0], pk[1], pk[2], pk[3]);
        }
        __syncthreads();

#pragma unroll
        for (int kk = 0; kk < 9; kk++) {
            short8 af[2];
#pragma unroll
            for (int mf = 0; mf < 2; mf++)
                af[mf] = *(const short8*)(a_lds + (mf * 16 + l15) * 296 + kk * 32 + lq * 8);
#pragma unroll
            for (int nf = 0; nf < 4; nf++) {
                int co = wc * 64 + nf * 16 + l15;
                short8 bf = *(const short8*)(wtb + ((size_t)(kk * C_ + co)) * C_ + ci0 + lq * 8);
#pragma unroll
                for (int mf = 0; mf < 2; mf++)
                    acc[mf][nf] = __builtin_amdgcn_mfma_f32_16x16x32_bf16(
                        af[mf], bf, acc[mf][nf], 0, 0, 0);
            }
        }
        __syncthreads();
    }

#pragma unroll
    for (int nf = 0; nf < 4; nf++) {
        int co = wc * 64 + nf * 16 + l15;
#pragma unroll
        for (int mf = 0; mf < 2; mf++) {
#pragma unroll
            for (int r = 0; r < 4; r++) {
                int px = px0 + mf * 16 + lq * 4 + r;
                out[(size_t)px * C_ + co] = fmaxf(acc[mf][nf][r], 0.f);
            }
        }
    }
}

// ---------------- 1x1 conv from NHWC fp32 feat, out NCHW fp32 ----------------
template <int NOg>
__global__ __launch_bounds__(256) void conv1x1_kernel(
    const float* __restrict__ feat, const float* __restrict__ w,
    const float* __restrict__ bias, const float* __restrict__ addsrc,
    float* __restrict__ outp, int O)
{
    const int lane = threadIdx.x & 63, og = threadIdx.x >> 6;
    const int px = blockIdx.x * 64 + lane;
    const int b = (px >= HW_) ? 1 : 0;
    const int rem = px - b * HW_;
    const float4* f = (const float4*)(feat + (size_t)px * C_);

    float acc[NOg];
#pragma unroll
    for (int j = 0; j < NOg; j++) acc[j] = 0.f;

    for (int c4 = 0; c4 < 64; c4++) {
        float4 v = f[c4];
#pragma unroll
        for (int j = 0; j < NOg; j++) {
            int o = og * NOg + j;
            if (o < O) {
                float4 w4 = ((const float4*)w)[o * 64 + c4];
                acc[j] = fmaf(v.x, w4.x, acc[j]);
                acc[j] = fmaf(v.y, w4.y, acc[j]);
                acc[j] = fmaf(v.z, w4.z, acc[j]);
                acc[j] = fmaf(v.w, w4.w, acc[j]);
            }
        }
    }
#pragma unroll
    for (int j = 0; j < NOg; j++) {
        int o = og * NOg + j;
        if (o < O) {
            float val = acc[j] + bias[o];
            size_t oi = ((size_t)(b * O + o)) * HW_ + rem;
            if (addsrc) val += addsrc[oi];
            outp[oi] = val;
        }
    }
}

// ---------------- host launch ----------------
extern "C" void kernel_launch(void* const* d_in, const int* in_sizes, int n_in,
                              void* d_out, int out_size, void* d_ws, size_t ws_size,
                              hipStream_t stream)
{
    (void)in_sizes; (void)n_in; (void)out_size; (void)ws_size;

    const float* x           = (const float*)d_in[0];
    const float* cls_w       = (const float*)d_in[1];
    const float* cls_b       = (const float*)d_in[2];
    const float* cls_gn_g    = (const float*)d_in[3];
    const float* cls_gn_b    = (const float*)d_in[4];
    const float* reg_w       = (const float*)d_in[5];
    const float* reg_b       = (const float*)d_in[6];
    const float* reg_gn_g    = (const float*)d_in[7];
    const float* reg_gn_b    = (const float*)d_in[8];
    const float* init_conv_w = (const float*)d_in[9];
    const float* init_conv_b = (const float*)d_in[10];
    const float* init_out_w  = (const float*)d_in[11];
    const float* init_out_b  = (const float*)d_in[12];
    const float* cls_dcn_w   = (const float*)d_in[13];
    const float* cls_out_w   = (const float*)d_in[14];
    const float* cls_out_b   = (const float*)d_in[15];
    const float* ref_dcn_w   = (const float*)d_in[16];
    const float* ref_out_w   = (const float*)d_in[17];
    const float* ref_out_b   = (const float*)d_in[18];

    float* out = (float*)d_out;
    float* ws  = (float*)d_ws;

    const size_t NF = (size_t)B_ * C_ * HW_;   // 7,782,400
    float* tmp32 = ws;
    unsigned short* xb16 = (unsigned short*)(ws + NF);
    unsigned short* bA   = xb16 + NF;
    unsigned short* bB   = bA + NF;
    unsigned short* clsF = bB + NF;
    unsigned short* ptsF = clsF + NF;
    unsigned short* wtb  = ptsF + NF;                  // 589,824 bf16
    float* stats = (float*)(wtb + 589824);             // 128 stats + 32 zero pad
    const unsigned short* zbuf = (const unsigned short*)(stats + 128);

    const dim3 mfmaGrid(10, 25, 2);       // 16-px x-tiles, 4-px y-tiles
    const dim3 wprepGrid(C_, 9);
    const dim3 nhwcGrid((HW_ + 63) / 64, C_ / 64, B_);
    const int  deformBlocks = (B_ * HW_) / 32;       // 950
    const int  px_blocks = (B_ * HW_) / 64;          // 475
    const int  gn_apply_blocks = (B_ * HW_ * 32) / 256;

    auto conv3 = [&](const unsigned short* src, float* dst, const float* wsrc,
                     const float* bias, float* st, int relu) {
        zero_stats_kernel<<<1, 256, 0, stream>>>(stats);
        wprep_kernel<<<wprepGrid, 256, 0, stream>>>(wsrc, wtb);
        conv3x3_mfma2_kernel<<<mfmaGrid, 256, 0, stream>>>(
            src, wtb, bias, dst, st, zbuf, relu);
    };
    auto gn = [&](const float* src, unsigned short* dstb,
                  const float* g, const float* be) {
        gn_apply_kernel<<<gn_apply_blocks, 256, 0, stream>>>(src, dstb, stats, g, be);
    };

    to_nhwc_b16_kernel<<<nhwcGrid, 256, 0, stream>>>(x, xb16);

    // --- cls tower ---
    conv3(xb16, tmp32, cls_w, cls_b, stats, 0);
    gn(tmp32, bA, cls_gn_g, cls_gn_b);
    conv3(bA, tmp32, cls_w + 1 * (size_t)C_ * CK, cls_b + C_, stats, 0);
    gn(tmp32, bB, cls_gn_g + C_, cls_gn_b + C_);
    conv3(bB, tmp32, cls_w + 2 * (size_t)C_ * CK, cls_b + 2 * C_, stats, 0);
    gn(tmp32, clsF, cls_gn_g + 2 * C_, cls_gn_b + 2 * C_);

    // --- pts tower ---
    conv3(xb16, tmp32, reg_w, reg_b, stats, 0);
    gn(tmp32, bA, reg_gn_g, reg_gn_b);
    conv3(bA, tmp32, reg_w + 1 * (size_t)C_ * CK, reg_b + C_, stats, 0);
    gn(tmp32, bB, reg_gn_g + C_, reg_gn_b + C_);
    conv3(bB, tmp32, reg_w + 2 * (size_t)C_ * CK, reg_b + 2 * C_, stats, 0);
    gn(tmp32, ptsF, reg_gn_g + 2 * C_, reg_gn_b + 2 * C_);

    // --- init branch ---
    conv3(ptsF, tmp32, init_conv_w, init_conv_b, nullptr, 1);
    conv1x1_kernel<5><<<px_blocks, 256, 0, stream>>>(
        tmp32, init_out_w, init_out_b, nullptr, out + OFF_INIT, 18);

    // --- cls deform + 1x1 ---
    wprep_kernel<<<wprepGrid, 256, 0, stream>>>(cls_dcn_w, wtb);
    deform_mfma_kernel<<<deformBlocks, 256, 0, stream>>>(clsF, out + OFF_INIT, wtb, tmp32);
    conv1x1_kernel<20><<<px_blocks, 256, 0, stream>>>(
        tmp32, cls_out_w, cls_out_b, nullptr, out, 80);

    // --- refine deform + 1x1 (+ pts_out_init) ---
    wprep_kernel<<<wprepGrid, 256, 0, stream>>>(ref_dcn_w, wtb);
    deform_mfma_kernel<<<deformBlocks, 256, 0, stream>>>(ptsF, out + OFF_INIT, wtb, tmp32);
    conv1x1_kernel<5><<<px_blocks, 256, 0, stream>>>(
        tmp32, ref_out_w, ref_out_b, out + OFF_INIT, out + OFF_REF, 18);
}

// Round 5
// 1260.007 us; speedup vs baseline: 4.2061x; 1.1323x over previous
//
#include <hip/hip_runtime.h>

// ---------------- problem constants ----------------
constexpr int B_  = 2;
constexpr int C_  = 256;
constexpr int H_  = 100;
constexpr int W_  = 152;
constexpr int HW_ = H_ * W_;          // 15200
constexpr int K9 = 9;
constexpr int CK = C_ * K9;           // 2304

constexpr int OFF_INIT = B_ * 80 * HW_;              // 2,432,000
constexpr int OFF_REF  = OFF_INIT + B_ * 18 * HW_;   // 2,979,200

typedef __attribute__((ext_vector_type(8))) short short8;
typedef __attribute__((ext_vector_type(4))) float f32x4;

__device__ inline unsigned short f2b(float f) {
    union { float f; unsigned u; } x; x.f = f;
    unsigned r = x.u + 0x7fff + ((x.u >> 16) & 1);   // RNE
    return (unsigned short)(r >> 16);
}
__device__ inline float b2f(unsigned short b) {
    union { unsigned u; float f; } x; x.u = ((unsigned)b) << 16; return x.f;
}

__device__ inline void load_lds16(const void* g, void* l) {
    __builtin_amdgcn_global_load_lds(
        (const __attribute__((address_space(1))) unsigned int*)g,
        (__attribute__((address_space(3))) unsigned int*)l, 16, 0, 0);
}

// ---------------- NCHW fp32 -> NHWC bf16 (input transform) ----------------
__global__ __launch_bounds__(256) void to_nhwc_b16_kernel(
    const float* __restrict__ in, unsigned short* __restrict__ outb)
{
    __shared__ float t[64][65];
    const int lane = threadIdx.x & 63, grp = threadIdx.x >> 6;
    const int p0 = blockIdx.x * 64;
    const int c0 = blockIdx.y * 64;
    const int b  = blockIdx.z;
#pragma unroll
    for (int j = 0; j < 16; j++) {
        int c = c0 + j * 4 + grp;
        int p = p0 + lane;
        float v = (p < HW_) ? in[((size_t)(b * C_ + c)) * HW_ + p] : 0.f;
        t[j * 4 + grp][lane] = v;
    }
    __syncthreads();
#pragma unroll
    for (int j = 0; j < 16; j++) {
        int p = p0 + j * 4 + grp;
        int c = c0 + lane;
        if (p < HW_) outb[((size_t)b * HW_ + p) * C_ + c] = f2b(t[lane][j * 4 + grp]);
    }
}

// ------- weight prep (dual): fp32 [co][ci][3][3] -> bf16 [kk][co][ci]; zero stats ----
__global__ void wprep2_kernel(const float* __restrict__ w0, const float* __restrict__ w1,
                              unsigned short* __restrict__ t0, unsigned short* __restrict__ t1,
                              float* __restrict__ stats)
{
    const int co = blockIdx.x, kk = blockIdx.y, tw = blockIdx.z, ci = threadIdx.x;
    const float* w = tw ? w1 : w0;
    unsigned short* t = tw ? t1 : t0;
    t[((size_t)kk * C_ + co) * C_ + ci] = f2b(w[((size_t)co * C_ + ci) * K9 + kk]);
    if (co == 0 && kk == 0 && tw == 0) {
        stats[ci] = 0.f;
        if (ci < 32) stats[256 + ci] = 0.f;   // zbuf
    }
}

// ---------------- MFMA conv3x3 (dual-tower) 2-phase dbuf + gload_lds + fused GN stats ---
// act NHWC bf16; wtb [kk][co][ci] bf16; out NHWC bf16 (pre-norm values when stats!=null).
// Block 256 thr = 4 waves; tile M=64px (4 rows x 16 cols) x N=256 co.
// grid.z: (tower<<1)|b.
__global__ __launch_bounds__(256) void conv3x3_mfma2_kernel(
    const unsigned short* __restrict__ src0, const unsigned short* __restrict__ src1,
    const unsigned short* __restrict__ wtb0, const unsigned short* __restrict__ wtb1,
    const float* __restrict__ bias0, const float* __restrict__ bias1,
    unsigned short* __restrict__ dst0, unsigned short* __restrict__ dst1,
    float* __restrict__ stats, const unsigned short* __restrict__ zbuf, int relu)
{
    __shared__ __align__(16) short a_lds[2][512 * 8];   // 2 x 8KB

    const int z = blockIdx.z, b = z & 1, tw = z >> 1;
    const unsigned short* act = tw ? src1 : src0;
    const unsigned short* wtb = tw ? wtb1 : wtb0;
    const float* bias = tw ? bias1 : bias0;
    unsigned short* out = tw ? dst1 : dst0;
    float* st = stats ? stats + tw * 128 : nullptr;

    const int tid = threadIdx.x;
    const int lane = tid & 63, wv = tid >> 6;
    const int l15 = lane & 15, lq = lane >> 4;
    const int x0 = blockIdx.x * 16, y0 = blockIdx.y * 4;

    // per-lane global sources for the 2 staging instructions of this wave
    const unsigned short* sbase[2];
    int sstep[2];
#pragma unroll
    for (int j = 0; j < 2; j++) {
        int p = (wv + j * 4) * 64 + lane;          // physical 16B unit
        int v = p ^ ((p >> 3) & 7);                // logical unit (involution)
        const unsigned short* src = zbuf;
        int step = 0;
        if (v < 432) {
            int px = v >> 2, q = v & 3;
            int row = px / 18, col = px - row * 18;
            int y = y0 - 1 + row, x = x0 - 1 + col;
            if (y >= 0 && y < H_ && x >= 0 && x < W_) {
                src = act + ((size_t)(b * HW_ + y * W_ + x) * C_ + q * 8);
                step = 1;
            }
        }
        sbase[j] = src; sstep[j] = step;
    }

    f32x4 acc[4][4];
#pragma unroll
    for (int mf = 0; mf < 4; mf++)
#pragma unroll
        for (int nf = 0; nf < 4; nf++) acc[mf][nf] = (f32x4){0.f, 0.f, 0.f, 0.f};

    auto STAGE = [&](int ci0, int bufi) {
#pragma unroll
        for (int j = 0; j < 2; j++)
            load_lds16(sbase[j] + sstep[j] * ci0,
                       &a_lds[bufi][((wv + j * 4) * 64) * 8]);
    };

    auto COMPUTE = [&](int ci0, int bufi) {
        const short* ab = a_lds[bufi];
#pragma unroll
        for (int kk = 0; kk < 9; kk++) {
            const int ky = kk / 3, kx = kk % 3;
            short8 af[4];
#pragma unroll
            for (int mf = 0; mf < 4; mf++) {
                int lv = ((mf + ky) * 18 + l15 + kx) * 4 + lq;
                int pu = lv ^ ((lv >> 3) & 7);
                af[mf] = *(const short8*)(ab + pu * 8);
            }
#pragma unroll
            for (int nf = 0; nf < 4; nf++) {
                int co = wv * 64 + nf * 16 + l15;
                short8 bf = *(const short8*)(wtb + ((size_t)(kk * C_ + co)) * C_ + ci0 + lq * 8);
#pragma unroll
                for (int mf = 0; mf < 4; mf++)
                    acc[mf][nf] = __builtin_amdgcn_mfma_f32_16x16x32_bf16(
                        af[mf], bf, acc[mf][nf], 0, 0, 0);
            }
        }
    };

    STAGE(0, 0);
    __syncthreads();
    for (int c = 0; c < 8; c++) {
        int cur = c & 1;
        if (c < 7) STAGE((c + 1) * 32, cur ^ 1);
        COMPUTE(c * 32, cur);
        __syncthreads();
    }

    // ---- epilogue: bias (+relu) store NHWC bf16, fused GN partial stats ----
#pragma unroll
    for (int nf = 0; nf < 4; nf++) {
        int co = wv * 64 + nf * 16 + l15;
        float bv = bias[co];
        float s = 0.f, ss = 0.f;
#pragma unroll
        for (int mf = 0; mf < 4; mf++) {
            int y = y0 + mf;
#pragma unroll
            for (int r = 0; r < 4; r++) {
                int x = x0 + lq * 4 + r;
                if (x < W_) {
                    float v = acc[mf][nf][r] + bv;
                    s += v; ss += v * v;
                    out[((size_t)(b * HW_ + y * W_ + x)) * C_ + co] =
                        f2b(relu ? fmaxf(v, 0.f) : v);
                }
            }
        }
        if (st) {
            s  += __shfl_xor(s, 1);  ss += __shfl_xor(ss, 1);
            s  += __shfl_xor(s, 2);  ss += __shfl_xor(ss, 2);
            s  += __shfl_xor(s, 4);  ss += __shfl_xor(ss, 4);
            s  += __shfl_xor(s, 16); ss += __shfl_xor(ss, 16);
            s  += __shfl_xor(s, 32); ss += __shfl_xor(ss, 32);
            if ((lane & 55) == 0) {
                int g = co >> 3;
                atomicAdd(&st[(b * 32 + g) * 2],     s);
                atomicAdd(&st[(b * 32 + g) * 2 + 1], ss);
            }
        }
    }
}

// ----- GN apply + ReLU, dual tower, IN PLACE on bf16 NHWC -----
__global__ __launch_bounds__(256) void gn2_apply_kernel(
    unsigned short* __restrict__ buf0, unsigned short* __restrict__ buf1,
    const float* __restrict__ stats,
    const float* __restrict__ g0, const float* __restrict__ be0,
    const float* __restrict__ g1, const float* __restrict__ be1)
{
    const int tw = blockIdx.y;
    unsigned short* buf = tw ? buf1 : buf0;
    const float* gamma = tw ? g1 : g0;
    const float* beta  = tw ? be1 : be0;
    const float* st = stats + tw * 128;

    const int i = blockIdx.x * 256 + threadIdx.x;   // chunk of 8 channels
    const int c8 = i & 31;            // == group id
    const int b = ((i >> 5) >= HW_) ? 1 : 0;
    const float inv_n = 1.f / (8.f * HW_);
    float s1 = st[(b * 32 + c8) * 2];
    float s2 = st[(b * 32 + c8) * 2 + 1];
    float mean = s1 * inv_n;
    float var  = s2 * inv_n - mean * mean;
    float rs = rsqrtf(var + 1e-5f);

    short8 v8 = *(const short8*)(buf + (size_t)i * 8);
    float vo[8];
#pragma unroll
    for (int j = 0; j < 8; j++) {
        int c = c8 * 8 + j;
        float ga = gamma[c] * rs;
        float be = beta[c] - mean * ga;
        vo[j] = fmaxf(fmaf(b2f((unsigned short)v8[j]), ga, be), 0.f);
    }
    unsigned pk[4];
#pragma unroll
    for (int j = 0; j < 4; j++)
        pk[j] = (unsigned)f2b(vo[2 * j]) | ((unsigned)f2b(vo[2 * j + 1]) << 16);
    *(int4*)(buf + (size_t)i * 8) = make_int4(pk[0], pk[1], pk[2], pk[3]);
}

// ---------------- MFMA deformable conv 3x3 (dual, + fused ReLU), out bf16 NHWC ----
__global__ __launch_bounds__(256) void deform2_mfma_kernel(
    const unsigned short* __restrict__ feat0, const unsigned short* __restrict__ feat1,
    const float* __restrict__ pts,
    const unsigned short* __restrict__ wtb0, const unsigned short* __restrict__ wtb1,
    unsigned short* __restrict__ out0, unsigned short* __restrict__ out1)
{
    __shared__ __align__(16) short a_lds[32 * 296];  // [px][kk*32+ci], pad 288->296
    __shared__ int   p_off[288][4];
    __shared__ float p_wgt[288][4];

    const int tw = blockIdx.y;
    const unsigned short* feat = tw ? feat1 : feat0;
    const unsigned short* wtb  = tw ? wtb1 : wtb0;
    unsigned short* out        = tw ? out1 : out0;

    const int tid = threadIdx.x;
    const int lane = tid & 63, wc = tid >> 6;
    const int l15 = lane & 15, lq = lane >> 4;
    const int px0 = blockIdx.x * 32;

    for (int pr = tid; pr < 288; pr += 256) {
        int px_l = pr / 9, kk = pr - px_l * 9;
        int px = px0 + px_l;
        int b = (px >= HW_) ? 1 : 0;
        int rem = px - b * HW_;
        int y = rem / W_, x = rem - y * W_;
        const float* pb = pts + ((size_t)b * 18 + 2 * kk) * HW_ + rem;
        float oy = pb[0], ox = pb[HW_];
        float gy = (float)y + oy, gx = (float)x + ox;
        float fy0 = floorf(gy), fx0 = floorf(gx);
        float dy = gy - fy0, dx = gx - fx0;
        int iy0 = (int)fy0, ix0 = (int)fx0;
        float wy[2] = {1.f - dy, dy}, wx[2] = {1.f - dx, dx};
#pragma unroll
        for (int cy = 0; cy < 2; cy++)
#pragma unroll
            for (int cx = 0; cx < 2; cx++) {
                int yy = iy0 + cy, xx = ix0 + cx;
                bool valid = (yy >= 0) && (yy < H_) && (xx >= 0) && (xx < W_);
                int yc = min(max(yy, 0), H_ - 1);
                int xc = min(max(xx, 0), W_ - 1);
                p_off[pr][cy * 2 + cx] = (b * HW_ + yc * W_ + xc) * C_;
                p_wgt[pr][cy * 2 + cx] = valid ? wy[cy] * wx[cx] : 0.f;
            }
    }

    f32x4 acc[2][4];
#pragma unroll
    for (int mf = 0; mf < 2; mf++)
#pragma unroll
        for (int nf = 0; nf < 4; nf++) acc[mf][nf] = (f32x4){0.f, 0.f, 0.f, 0.f};

    __syncthreads();

    for (int ci0 = 0; ci0 < C_; ci0 += 32) {
        for (int u = tid; u < 1152; u += 256) {
            int q = u & 3, pr = u >> 2;
            int px_l = pr / 9, kk = pr - px_l * 9;
            int4  of = *(const int4*)p_off[pr];
            float4 wg = *(const float4*)p_wgt[pr];
            const unsigned short* fb = feat + ci0 + q * 8;
            short8 v0 = *(const short8*)(fb + of.x);
            short8 v1 = *(const short8*)(fb + of.y);
            short8 v2 = *(const short8*)(fb + of.z);
            short8 v3 = *(const short8*)(fb + of.w);
            unsigned pk[4];
#pragma unroll
            for (int j = 0; j < 4; j++) {
                float r0 = wg.x * b2f((unsigned short)v0[2 * j])
                         + wg.y * b2f((unsigned short)v1[2 * j])
                         + wg.z * b2f((unsigned short)v2[2 * j])
                         + wg.w * b2f((unsigned short)v3[2 * j]);
                float r1 = wg.x * b2f((unsigned short)v0[2 * j + 1])
                         + wg.y * b2f((unsigned short)v1[2 * j + 1])
                         + wg.z * b2f((unsigned short)v2[2 * j + 1])
                         + wg.w * b2f((unsigned short)v3[2 * j + 1]);
                pk[j] = (unsigned)f2b(r0) | ((unsigned)f2b(r1) << 16);
            }
            *(int4*)(a_lds + px_l * 296 + kk * 32 + q * 8) = make_int4(pk[0], pk[1], pk[2], pk[3]);
        }
        __syncthreads();

#pragma unroll
        for (int kk = 0; kk < 9; kk++) {
            short8 af[2];
#pragma unroll
            for (int mf = 0; mf < 2; mf++)
                af[mf] = *(const short8*)(a_lds + (mf * 16 + l15) * 296 + kk * 32 + lq * 8);
#pragma unroll
            for (int nf = 0; nf < 4; nf++) {
                int co = wc * 64 + nf * 16 + l15;
                short8 bf = *(const short8*)(wtb + ((size_t)(kk * C_ + co)) * C_ + ci0 + lq * 8);
#pragma unroll
                for (int mf = 0; mf < 2; mf++)
                    acc[mf][nf] = __builtin_amdgcn_mfma_f32_16x16x32_bf16(
                        af[mf], bf, acc[mf][nf], 0, 0, 0);
            }
        }
        __syncthreads();
    }

#pragma unroll
    for (int nf = 0; nf < 4; nf++) {
        int co = wc * 64 + nf * 16 + l15;
#pragma unroll
        for (int mf = 0; mf < 2; mf++) {
#pragma unroll
            for (int r = 0; r < 4; r++) {
                int px = px0 + mf * 16 + lq * 4 + r;
                out[(size_t)px * C_ + co] = f2b(fmaxf(acc[mf][nf][r], 0.f));
            }
        }
    }
}

// ---------------- 1x1 conv from NHWC bf16 feat, out NCHW fp32 ----------------
template <int NOg>
__global__ __launch_bounds__(256) void conv1x1_kernel(
    const unsigned short* __restrict__ feat, const float* __restrict__ w,
    const float* __restrict__ bias, const float* __restrict__ addsrc,
    float* __restrict__ outp, int O)
{
    const int lane = threadIdx.x & 63, og = threadIdx.x >> 6;
    const int px = blockIdx.x * 64 + lane;
    const int b = (px >= HW_) ? 1 : 0;
    const int rem = px - b * HW_;
    const short8* f8 = (const short8*)(feat + (size_t)px * C_);

    float acc[NOg];
#pragma unroll
    for (int j = 0; j < NOg; j++) acc[j] = 0.f;

    for (int c8 = 0; c8 < 32; c8++) {
        short8 v8 = f8[c8];
        float vf[8];
#pragma unroll
        for (int e = 0; e < 8; e++) vf[e] = b2f((unsigned short)v8[e]);
#pragma unroll
        for (int j = 0; j < NOg; j++) {
            int o = og * NOg + j;
            if (o < O) {
                const float* wr = w + (size_t)o * C_ + c8 * 8;
                float4 w0 = *(const float4*)wr;
                float4 w1 = *(const float4*)(wr + 4);
                acc[j] = fmaf(vf[0], w0.x, acc[j]);
                acc[j] = fmaf(vf[1], w0.y, acc[j]);
                acc[j] = fmaf(vf[2], w0.z, acc[j]);
                acc[j] = fmaf(vf[3], w0.w, acc[j]);
                acc[j] = fmaf(vf[4], w1.x, acc[j]);
                acc[j] = fmaf(vf[5], w1.y, acc[j]);
                acc[j] = fmaf(vf[6], w1.z, acc[j]);
                acc[j] = fmaf(vf[7], w1.w, acc[j]);
            }
        }
    }
#pragma unroll
    for (int j = 0; j < NOg; j++) {
        int o = og * NOg + j;
        if (o < O) {
            float val = acc[j] + bias[o];
            size_t oi = ((size_t)(b * O + o)) * HW_ + rem;
            if (addsrc) val += addsrc[oi];
            outp[oi] = val;
        }
    }
}

// ---------------- host launch ----------------
extern "C" void kernel_launch(void* const* d_in, const int* in_sizes, int n_in,
                              void* d_out, int out_size, void* d_ws, size_t ws_size,
                              hipStream_t stream)
{
    (void)in_sizes; (void)n_in; (void)out_size; (void)ws_size;

    const float* x           = (const float*)d_in[0];
    const float* cls_w       = (const float*)d_in[1];
    const float* cls_b       = (const float*)d_in[2];
    const float* cls_gn_g    = (const float*)d_in[3];
    const float* cls_gn_b    = (const float*)d_in[4];
    const float* reg_w       = (const float*)d_in[5];
    const float* reg_b       = (const float*)d_in[6];
    const float* reg_gn_g    = (const float*)d_in[7];
    const float* reg_gn_b    = (const float*)d_in[8];
    const float* init_conv_w = (const float*)d_in[9];
    const float* init_conv_b = (const float*)d_in[10];
    const float* init_out_w  = (const float*)d_in[11];
    const float* init_out_b  = (const float*)d_in[12];
    const float* cls_dcn_w   = (const float*)d_in[13];
    const float* cls_out_w   = (const float*)d_in[14];
    const float* cls_out_b   = (const float*)d_in[15];
    const float* ref_dcn_w   = (const float*)d_in[16];
    const float* ref_out_w   = (const float*)d_in[17];
    const float* ref_out_b   = (const float*)d_in[18];

    float* out = (float*)d_out;

    const size_t NF = (size_t)B_ * C_ * HW_;   // 7,782,400 elements
    unsigned short* xb16 = (unsigned short*)d_ws;
    unsigned short* bA   = xb16 + NF;
    unsigned short* bB   = bA + NF;
    unsigned short* bC   = bB + NF;
    unsigned short* bD   = bC + NF;
    unsigned short* wtb0 = bD + NF;                    // 589,824 bf16
    unsigned short* wtb1 = wtb0 + (size_t)CK * C_;
    float* stats = (float*)(wtb1 + (size_t)CK * C_);   // 256 stats + 32 zbuf
    const unsigned short* zbuf = (const unsigned short*)(stats + 256);

    const dim3 convGrid2(10, 25, 4);      // dual tower
    const dim3 convGrid1(10, 25, 2);      // single tower
    const dim3 wprepGrid2(C_, 9, 2);
    const dim3 wprepGrid1(C_, 9, 1);
    const dim3 nhwcGrid((HW_ + 63) / 64, C_ / 64, B_);
    const dim3 gnGrid((B_ * HW_ * 32) / 256, 2);
    const dim3 deformGrid((B_ * HW_) / 32, 2);       // (950, 2)
    const int  px_blocks = (B_ * HW_) / 64;          // 475

    to_nhwc_b16_kernel<<<nhwcGrid, 256, 0, stream>>>(x, xb16);

    // --- stage 0: xb16 -> bA (cls), bC (pts) ---
    wprep2_kernel<<<wprepGrid2, 256, 0, stream>>>(cls_w, reg_w, wtb0, wtb1, stats);
    conv3x3_mfma2_kernel<<<convGrid2, 256, 0, stream>>>(
        xb16, xb16, wtb0, wtb1, cls_b, reg_b, bA, bC, stats, zbuf, 0);
    gn2_apply_kernel<<<gnGrid, 256, 0, stream>>>(
        bA, bC, stats, cls_gn_g, cls_gn_b, reg_gn_g, reg_gn_b);

    // --- stage 1: bA -> bB, bC -> bD ---
    wprep2_kernel<<<wprepGrid2, 256, 0, stream>>>(
        cls_w + (size_t)C_ * CK, reg_w + (size_t)C_ * CK, wtb0, wtb1, stats);
    conv3x3_mfma2_kernel<<<convGrid2, 256, 0, stream>>>(
        bA, bC, wtb0, wtb1, cls_b + C_, reg_b + C_, bB, bD, stats, zbuf, 0);
    gn2_apply_kernel<<<gnGrid, 256, 0, stream>>>(
        bB, bD, stats, cls_gn_g + C_, cls_gn_b + C_, reg_gn_g + C_, reg_gn_b + C_);

    // --- stage 2: bB -> bA (clsF), bD -> bC (ptsF) ---
    wprep2_kernel<<<wprepGrid2, 256, 0, stream>>>(
        cls_w + 2 * (size_t)C_ * CK, reg_w + 2 * (size_t)C_ * CK, wtb0, wtb1, stats);
    conv3x3_mfma2_kernel<<<convGrid2, 256, 0, stream>>>(
        bB, bD, wtb0, wtb1, cls_b + 2 * C_, reg_b + 2 * C_, bA, bC, stats, zbuf, 0);
    gn2_apply_kernel<<<gnGrid, 256, 0, stream>>>(
        bA, bC, stats, cls_gn_g + 2 * C_, cls_gn_b + 2 * C_,
        reg_gn_g + 2 * C_, reg_gn_b + 2 * C_);

    // --- init branch: relu(conv3x3(ptsF=bC)) -> bD -> 1x1 -> pts_out_init ---
    wprep2_kernel<<<wprepGrid1, 256, 0, stream>>>(init_conv_w, nullptr, wtb0, nullptr, stats);
    conv3x3_mfma2_kernel<<<convGrid1, 256, 0, stream>>>(
        bC, nullptr, wtb0, nullptr, init_conv_b, nullptr, bD, nullptr, nullptr, zbuf, 1);
    conv1x1_kernel<5><<<px_blocks, 256, 0, stream>>>(
        bD, init_out_w, init_out_b, nullptr, out + OFF_INIT, 18);

    // --- both deforms in one dispatch: clsF->bB, ptsF->bD ---
    wprep2_kernel<<<wprepGrid2, 256, 0, stream>>>(cls_dcn_w, ref_dcn_w, wtb0, wtb1, stats);
    deform2_mfma_kernel<<<deformGrid, 256, 0, stream>>>(
        bA, bC, out + OFF_INIT, wtb0, wtb1, bB, bD);

    // --- tails ---
    conv1x1_kernel<20><<<px_blocks, 256, 0, stream>>>(
        bB, cls_out_w, cls_out_b, nullptr, out, 80);
    conv1x1_kernel<5><<<px_blocks, 256, 0, stream>>>(
        bD, ref_out_w, ref_out_b, out + OFF_INIT, out + OFF_REF, 18);
}

// Round 6
// 1202.664 us; speedup vs baseline: 4.4067x; 1.0477x over previous
//
#include <hip/hip_runtime.h>

// ---------------- problem constants ----------------
constexpr int B_  = 2;
constexpr int C_  = 256;
constexpr int H_  = 100;
constexpr int W_  = 152;
constexpr int HW_ = H_ * W_;          // 15200
constexpr int K9 = 9;
constexpr int CK = C_ * K9;           // 2304

constexpr int OFF_INIT = B_ * 80 * HW_;              // 2,432,000
constexpr int OFF_REF  = OFF_INIT + B_ * 18 * HW_;   // 2,979,200

typedef __attribute__((ext_vector_type(8))) short short8;
typedef __attribute__((ext_vector_type(4))) float f32x4;

__device__ inline unsigned short f2b(float f) {
    union { float f; unsigned u; } x; x.f = f;
    unsigned r = x.u + 0x7fff + ((x.u >> 16) & 1);   // RNE
    return (unsigned short)(r >> 16);
}
__device__ inline float b2f(unsigned short b) {
    union { unsigned u; float f; } x; x.u = ((unsigned)b) << 16; return x.f;
}

__device__ inline void load_lds16(const void* g, void* l) {
    __builtin_amdgcn_global_load_lds(
        (const __attribute__((address_space(1))) unsigned int*)g,
        (__attribute__((address_space(3))) unsigned int*)l, 16, 0, 0);
}

// ---------------- NCHW fp32 -> NHWC bf16 (input transform) ----------------
__global__ __launch_bounds__(256) void to_nhwc_b16_kernel(
    const float* __restrict__ in, unsigned short* __restrict__ outb)
{
    __shared__ float t[64][65];
    const int lane = threadIdx.x & 63, grp = threadIdx.x >> 6;
    const int p0 = blockIdx.x * 64;
    const int c0 = blockIdx.y * 64;
    const int b  = blockIdx.z;
#pragma unroll
    for (int j = 0; j < 16; j++) {
        int c = c0 + j * 4 + grp;
        int p = p0 + lane;
        float v = (p < HW_) ? in[((size_t)(b * C_ + c)) * HW_ + p] : 0.f;
        t[j * 4 + grp][lane] = v;
    }
    __syncthreads();
#pragma unroll
    for (int j = 0; j < 16; j++) {
        int p = p0 + j * 4 + grp;
        int c = c0 + lane;
        if (p < HW_) outb[((size_t)b * HW_ + p) * C_ + c] = f2b(t[lane][j * 4 + grp]);
    }
}

// ------- weight prep (dual): fp32 [co][ci][3][3] -> bf16 [kk][co][ci]; zero stats ----
__global__ void wprep2_kernel(const float* __restrict__ w0, const float* __restrict__ w1,
                              unsigned short* __restrict__ t0, unsigned short* __restrict__ t1,
                              float* __restrict__ stats)
{
    const int co = blockIdx.x, kk = blockIdx.y, tw = blockIdx.z, ci = threadIdx.x;
    const float* w = tw ? w1 : w0;
    unsigned short* t = tw ? t1 : t0;
    t[((size_t)kk * C_ + co) * C_ + ci] = f2b(w[((size_t)co * C_ + ci) * K9 + kk]);
    if (co == 0 && kk == 0 && tw == 0) {
        stats[ci] = 0.f;
        if (ci < 32) stats[256 + ci] = 0.f;   // zbuf
    }
}

// ---------------- MFMA conv3x3 v3: M=128 (4r x 32c) x N=256, 8 waves ----------------
// act NHWC bf16; wtb [kk][co][ci] bf16; out NHWC bf16 (pre-norm when stats given).
// A-halo per 32-ci chunk: 6 rows x 34 cols -> 816 16B units, padded to 1024,
// XOR-swizzled (u ^= (u>>3)&7) with inverse-swizzled global source. Double-buffered.
__global__ __launch_bounds__(512) void conv3x3_mfma3_kernel(
    const unsigned short* __restrict__ src0, const unsigned short* __restrict__ src1,
    const unsigned short* __restrict__ wtb0, const unsigned short* __restrict__ wtb1,
    const float* __restrict__ bias0, const float* __restrict__ bias1,
    unsigned short* __restrict__ dst0, unsigned short* __restrict__ dst1,
    float* __restrict__ stats, const unsigned short* __restrict__ zbuf, int relu)
{
    __shared__ __align__(16) short a_lds[2][1024 * 8];   // 2 x 16KB

    const int z = blockIdx.z, b = z & 1, tw = z >> 1;
    const unsigned short* act = tw ? src1 : src0;
    const unsigned short* wtb = tw ? wtb1 : wtb0;
    const float* bias = tw ? bias1 : bias0;
    unsigned short* out = tw ? dst1 : dst0;
    float* st = stats ? stats + tw * 128 : nullptr;

    const int tid = threadIdx.x;
    const int lane = tid & 63, wid = tid >> 6;
    const int wr = wid >> 2, wc = wid & 3;       // wr: x-half, wc: co quadrant
    const int l15 = lane & 15, lq = lane >> 4;
    const int x0 = blockIdx.x * 32, y0 = blockIdx.y * 4;

    // per-lane global sources for the 2 staging instructions
    const unsigned short* sbase[2];
    int sstep[2];
#pragma unroll
    for (int j = 0; j < 2; j++) {
        int p = (wid + j * 8) * 64 + lane;         // physical 16B unit, 0..1023
        int v = p ^ ((p >> 3) & 7);                // logical unit (involution)
        const unsigned short* src = zbuf;
        int step = 0;
        if (v < 816) {
            int pix = v >> 2, q = v & 3;
            int row = pix / 34, col = pix - row * 34;
            int y = y0 - 1 + row, x = x0 - 1 + col;
            if (y >= 0 && y < H_ && x >= 0 && x < W_) {
                src = act + ((size_t)(b * HW_ + y * W_ + x) * C_ + q * 8);
                step = 1;
            }
        }
        sbase[j] = src; sstep[j] = step;
    }

    f32x4 acc[4][4];
#pragma unroll
    for (int mf = 0; mf < 4; mf++)
#pragma unroll
        for (int nf = 0; nf < 4; nf++) acc[mf][nf] = (f32x4){0.f, 0.f, 0.f, 0.f};

    auto STAGE = [&](int ci0, int bufi) {
#pragma unroll
        for (int j = 0; j < 2; j++)
            load_lds16(sbase[j] + sstep[j] * ci0,
                       &a_lds[bufi][((wid + j * 8) * 64 + lane) * 8]);
    };

    auto COMPUTE = [&](int ci0, int bufi) {
        const short* ab = a_lds[bufi];
#pragma unroll
        for (int kk = 0; kk < 9; kk++) {
            const int ky = kk / 3, kx = kk % 3;
            short8 af[4];
#pragma unroll
            for (int mf = 0; mf < 4; mf++) {
                int lv = ((mf + ky) * 34 + wr * 16 + l15 + kx) * 4 + lq;
                int pu = lv ^ ((lv >> 3) & 7);
                af[mf] = *(const short8*)(ab + pu * 8);
            }
#pragma unroll
            for (int nf = 0; nf < 4; nf++) {
                int co = wc * 64 + nf * 16 + l15;
                short8 bf = *(const short8*)(wtb + ((size_t)(kk * C_ + co)) * C_ + ci0 + lq * 8);
#pragma unroll
                for (int mf = 0; mf < 4; mf++)
                    acc[mf][nf] = __builtin_amdgcn_mfma_f32_16x16x32_bf16(
                        af[mf], bf, acc[mf][nf], 0, 0, 0);
            }
        }
    };

    STAGE(0, 0);
    __syncthreads();
    for (int c = 0; c < 8; c++) {
        int cur = c & 1;
        if (c < 7) STAGE((c + 1) * 32, cur ^ 1);
        COMPUTE(c * 32, cur);
        __syncthreads();
    }

    // ---- epilogue: bias (+relu) store NHWC bf16, fused GN partial stats ----
#pragma unroll
    for (int nf = 0; nf < 4; nf++) {
        int co = wc * 64 + nf * 16 + l15;
        float bv = bias[co];
        float s = 0.f, ss = 0.f;
#pragma unroll
        for (int mf = 0; mf < 4; mf++) {
            int y = y0 + mf;                        // always < 100 (25 y-tiles)
#pragma unroll
            for (int r = 0; r < 4; r++) {
                int x = x0 + wr * 16 + lq * 4 + r;
                if (x < W_) {
                    float v = acc[mf][nf][r] + bv;
                    s += v; ss += v * v;
                    out[((size_t)(b * HW_ + y * W_ + x)) * C_ + co] =
                        f2b(relu ? fmaxf(v, 0.f) : v);
                }
            }
        }
        if (st) {
            s  += __shfl_xor(s, 1);  ss += __shfl_xor(ss, 1);
            s  += __shfl_xor(s, 2);  ss += __shfl_xor(ss, 2);
            s  += __shfl_xor(s, 4);  ss += __shfl_xor(ss, 4);
            s  += __shfl_xor(s, 16); ss += __shfl_xor(ss, 16);
            s  += __shfl_xor(s, 32); ss += __shfl_xor(ss, 32);
            if ((lane & 55) == 0) {
                int g = co >> 3;
                atomicAdd(&st[(b * 32 + g) * 2],     s);
                atomicAdd(&st[(b * 32 + g) * 2 + 1], ss);
            }
        }
    }
}

// ----- GN apply + ReLU, dual tower, IN PLACE on bf16 NHWC -----
__global__ __launch_bounds__(256) void gn2_apply_kernel(
    unsigned short* __restrict__ buf0, unsigned short* __restrict__ buf1,
    const float* __restrict__ stats,
    const float* __restrict__ g0, const float* __restrict__ be0,
    const float* __restrict__ g1, const float* __restrict__ be1)
{
    const int tw = blockIdx.y;
    unsigned short* buf = tw ? buf1 : buf0;
    const float* gamma = tw ? g1 : g0;
    const float* beta  = tw ? be1 : be0;
    const float* st = stats + tw * 128;

    const int i = blockIdx.x * 256 + threadIdx.x;   // chunk of 8 channels
    const int c8 = i & 31;            // == group id
    const int b = ((i >> 5) >= HW_) ? 1 : 0;
    const float inv_n = 1.f / (8.f * HW_);
    float s1 = st[(b * 32 + c8) * 2];
    float s2 = st[(b * 32 + c8) * 2 + 1];
    float mean = s1 * inv_n;
    float var  = s2 * inv_n - mean * mean;
    float rs = rsqrtf(var + 1e-5f);

    short8 v8 = *(const short8*)(buf + (size_t)i * 8);
    float vo[8];
#pragma unroll
    for (int j = 0; j < 8; j++) {
        int c = c8 * 8 + j;
        float ga = gamma[c] * rs;
        float be = beta[c] - mean * ga;
        vo[j] = fmaxf(fmaf(b2f((unsigned short)v8[j]), ga, be), 0.f);
    }
    unsigned pk[4];
#pragma unroll
    for (int j = 0; j < 4; j++)
        pk[j] = (unsigned)f2b(vo[2 * j]) | ((unsigned)f2b(vo[2 * j + 1]) << 16);
    *(int4*)(buf + (size_t)i * 8) = make_int4(pk[0], pk[1], pk[2], pk[3]);
}

// ---------------- MFMA deformable conv v3: LDS-windowed sampling ----------------
// Tile 4x8 px; feature window 8 rows x 12 cols staged coalesced per ci-chunk.
// Corner out of window -> global fallback (encoded ref<0). out bf16 NHWC.
__global__ __launch_bounds__(256) void deform3_mfma_kernel(
    const unsigned short* __restrict__ feat0, const unsigned short* __restrict__ feat1,
    const float* __restrict__ pts,
    const unsigned short* __restrict__ wtb0, const unsigned short* __restrict__ wtb1,
    unsigned short* __restrict__ out0, unsigned short* __restrict__ out1,
    const unsigned short* __restrict__ zbuf)
{
    __shared__ __align__(16) short s_lds[32 * 296];   // A-tile [px][kk*32+ci] pad
    __shared__ __align__(16) short f_lds[512 * 8];    // feat window (384 real + pad)
    __shared__ int   p_ref[288][4];
    __shared__ float p_wgt[288][4];

    const int z = blockIdx.z, b = z & 1, tw = z >> 1;
    const unsigned short* feat = tw ? feat1 : feat0;
    const unsigned short* wtb  = tw ? wtb1 : wtb0;
    unsigned short* out        = tw ? out1 : out0;

    const int tid = threadIdx.x;
    const int lane = tid & 63, wc = tid >> 6;
    const int l15 = lane & 15, lq = lane >> 4;
    const int x0 = blockIdx.x * 8, y0 = blockIdx.y * 4;

    // ---- staging sources (2 per thread) for the 8x12 window ----
    const unsigned short* sbase[2];
    int sstep[2];
#pragma unroll
    for (int j = 0; j < 2; j++) {
        int p = (wc + j * 4) * 64 + lane;          // physical unit 0..511
        int v = p ^ ((p >> 3) & 7);                // logical
        const unsigned short* src = zbuf;
        int step = 0;
        if (v < 384) {
            int pix = v >> 2, q = v & 3;
            int wy = pix / 12, wx = pix - wy * 12;
            int y = y0 - 2 + wy, x = x0 - 2 + wx;
            if (y >= 0 && y < H_ && x >= 0 && x < W_) {
                src = feat + ((size_t)(b * HW_ + y * W_ + x) * C_ + q * 8);
                step = 1;
            }
        }
        sbase[j] = src; sstep[j] = step;
    }

    // ---- bilinear setup: 288 (px,tap) pairs ----
    for (int pr = tid; pr < 288; pr += 256) {
        int px_l = pr / 9, kk = pr - px_l * 9;
        int y = y0 + (px_l >> 3), x = x0 + (px_l & 7);
        const float* pb = pts + ((size_t)b * 18 + 2 * kk) * HW_ + y * W_ + x;
        float oy = pb[0], ox = pb[HW_];
        float gy = (float)y + oy, gx = (float)x + ox;
        float fy0 = floorf(gy), fx0 = floorf(gx);
        float dy = gy - fy0, dx = gx - fx0;
        int iy0 = (int)fy0, ix0 = (int)fx0;
        float wy2[2] = {1.f - dy, dy}, wx2[2] = {1.f - dx, dx};
#pragma unroll
        for (int cy = 0; cy < 2; cy++)
#pragma unroll
            for (int cx = 0; cx < 2; cx++) {
                int yy = iy0 + cy, xx = ix0 + cx;
                bool valid = (yy >= 0) && (yy < H_) && (xx >= 0) && (xx < W_);
                int ref = 0;
                float w = 0.f;
                if (valid) {
                    w = wy2[cy] * wx2[cx];
                    int wy = yy - (y0 - 2), wx = xx - (x0 - 2);
                    if (wy >= 0 && wy < 8 && wx >= 0 && wx < 12)
                        ref = wy * 12 + wx;                       // in-window
                    else
                        ref = -(int)((b * HW_ + yy * W_ + xx) * C_) - 1;  // global
                }
                p_ref[pr][cy * 2 + cx] = ref;
                p_wgt[pr][cy * 2 + cx] = w;
            }
    }

    f32x4 acc[2][4];
#pragma unroll
    for (int mf = 0; mf < 2; mf++)
#pragma unroll
        for (int nf = 0; nf < 4; nf++) acc[mf][nf] = (f32x4){0.f, 0.f, 0.f, 0.f};

    auto STAGE = [&](int ci0) {
#pragma unroll
        for (int j = 0; j < 2; j++)
            load_lds16(sbase[j] + sstep[j] * ci0,
                       &f_lds[((wc + j * 4) * 64 + lane) * 8]);
    };

    STAGE(0);
    __syncthreads();

    for (int c = 0; c < 8; c++) {
        const int ci0 = c * 32;
        // ---- sample A-tile from LDS window (global fallback if ref<0) ----
        for (int u = tid; u < 1152; u += 256) {
            int q = u & 3, pr = u >> 2;
            int px_l = pr / 9, kk = pr - px_l * 9;
            int4  rf = *(const int4*)p_ref[pr];
            float4 wg = *(const float4*)p_wgt[pr];
            short8 cv[4];
            int rr[4] = {rf.x, rf.y, rf.z, rf.w};
#pragma unroll
            for (int j = 0; j < 4; j++) {
                if (rr[j] >= 0) {
                    int uu = rr[j] * 4 + q;
                    int pu = uu ^ ((uu >> 3) & 7);
                    cv[j] = *(const short8*)(f_lds + pu * 8);
                } else {
                    cv[j] = *(const short8*)(feat + (-rr[j] - 1) + ci0 + q * 8);
                }
            }
            unsigned pk[4];
#pragma unroll
            for (int j = 0; j < 4; j++) {
                float r0 = wg.x * b2f((unsigned short)cv[0][2 * j])
                         + wg.y * b2f((unsigned short)cv[1][2 * j])
                         + wg.z * b2f((unsigned short)cv[2][2 * j])
                         + wg.w * b2f((unsigned short)cv[3][2 * j]);
                float r1 = wg.x * b2f((unsigned short)cv[0][2 * j + 1])
                         + wg.y * b2f((unsigned short)cv[1][2 * j + 1])
                         + wg.z * b2f((unsigned short)cv[2][2 * j + 1])
                         + wg.w * b2f((unsigned short)cv[3][2 * j + 1]);
                pk[j] = (unsigned)f2b(r0) | ((unsigned)f2b(r1) << 16);
            }
            *(int4*)(s_lds + px_l * 296 + kk * 32 + q * 8) = make_int4(pk[0], pk[1], pk[2], pk[3]);
        }
        __syncthreads();            // A complete; feat window consumed
        if (c < 7) STAGE(ci0 + 32); // restage window (latency hidden by MFMA)

        // ---- MFMA over 9 taps ----
#pragma unroll
        for (int kk = 0; kk < 9; kk++) {
            short8 af[2];
#pragma unroll
            for (int mf = 0; mf < 2; mf++)
                af[mf] = *(const short8*)(s_lds + (mf * 16 + l15) * 296 + kk * 32 + lq * 8);
#pragma unroll
            for (int nf = 0; nf < 4; nf++) {
                int co = wc * 64 + nf * 16 + l15;
                short8 bf = *(const short8*)(wtb + ((size_t)(kk * C_ + co)) * C_ + ci0 + lq * 8);
#pragma unroll
                for (int mf = 0; mf < 2; mf++)
                    acc[mf][nf] = __builtin_amdgcn_mfma_f32_16x16x32_bf16(
                        af[mf], bf, acc[mf][nf], 0, 0, 0);
            }
        }
        __syncthreads();            // stage drained (vmcnt0); A free
    }

    // ---- epilogue: relu -> bf16 NHWC ----
#pragma unroll
    for (int nf = 0; nf < 4; nf++) {
        int co = wc * 64 + nf * 16 + l15;
#pragma unroll
        for (int mf = 0; mf < 2; mf++) {
#pragma unroll
            for (int r = 0; r < 4; r++) {
                int px_l = mf * 16 + lq * 4 + r;
                int y = y0 + (px_l >> 3), x = x0 + (px_l & 7);
                out[((size_t)(b * HW_ + y * W_ + x)) * C_ + co] =
                    f2b(fmaxf(acc[mf][nf][r], 0.f));
            }
        }
    }
}

// ---------------- 1x1 conv from NHWC bf16 feat, out NCHW fp32 ----------------
template <int NOg>
__global__ __launch_bounds__(256) void conv1x1_kernel(
    const unsigned short* __restrict__ feat, const float* __restrict__ w,
    const float* __restrict__ bias, const float* __restrict__ addsrc,
    float* __restrict__ outp, int O)
{
    const int lane = threadIdx.x & 63, og = threadIdx.x >> 6;
    const int px = blockIdx.x * 64 + lane;
    const int b = (px >= HW_) ? 1 : 0;
    const int rem = px - b * HW_;
    const short8* f8 = (const short8*)(feat + (size_t)px * C_);

    float acc[NOg];
#pragma unroll
    for (int j = 0; j < NOg; j++) acc[j] = 0.f;

    for (int c8 = 0; c8 < 32; c8++) {
        short8 v8 = f8[c8];
        float vf[8];
#pragma unroll
        for (int e = 0; e < 8; e++) vf[e] = b2f((unsigned short)v8[e]);
#pragma unroll
        for (int j = 0; j < NOg; j++) {
            int o = og * NOg + j;
            if (o < O) {
                const float* wr = w + (size_t)o * C_ + c8 * 8;
                float4 w0 = *(const float4*)wr;
                float4 w1 = *(const float4*)(wr + 4);
                acc[j] = fmaf(vf[0], w0.x, acc[j]);
                acc[j] = fmaf(vf[1], w0.y, acc[j]);
                acc[j] = fmaf(vf[2], w0.z, acc[j]);
                acc[j] = fmaf(vf[3], w0.w, acc[j]);
                acc[j] = fmaf(vf[4], w1.x, acc[j]);
                acc[j] = fmaf(vf[5], w1.y, acc[j]);
                acc[j] = fmaf(vf[6], w1.z, acc[j]);
                acc[j] = fmaf(vf[7], w1.w, acc[j]);
            }
        }
    }
#pragma unroll
    for (int j = 0; j < NOg; j++) {
        int o = og * NOg + j;
        if (o < O) {
            float val = acc[j] + bias[o];
            size_t oi = ((size_t)(b * O + o)) * HW_ + rem;
            if (addsrc) val += addsrc[oi];
            outp[oi] = val;
        }
    }
}

// ---------------- host launch ----------------
extern "C" void kernel_launch(void* const* d_in, const int* in_sizes, int n_in,
                              void* d_out, int out_size, void* d_ws, size_t ws_size,
                              hipStream_t stream)
{
    (void)in_sizes; (void)n_in; (void)out_size; (void)ws_size;

    const float* x           = (const float*)d_in[0];
    const float* cls_w       = (const float*)d_in[1];
    const float* cls_b       = (const float*)d_in[2];
    const float* cls_gn_g    = (const float*)d_in[3];
    const float* cls_gn_b    = (const float*)d_in[4];
    const float* reg_w       = (const float*)d_in[5];
    const float* reg_b       = (const float*)d_in[6];
    const float* reg_gn_g    = (const float*)d_in[7];
    const float* reg_gn_b    = (const float*)d_in[8];
    const float* init_conv_w = (const float*)d_in[9];
    const float* init_conv_b = (const float*)d_in[10];
    const float* init_out_w  = (const float*)d_in[11];
    const float* init_out_b  = (const float*)d_in[12];
    const float* cls_dcn_w   = (const float*)d_in[13];
    const float* cls_out_w   = (const float*)d_in[14];
    const float* cls_out_b   = (const float*)d_in[15];
    const float* ref_dcn_w   = (const float*)d_in[16];
    const float* ref_out_w   = (const float*)d_in[17];
    const float* ref_out_b   = (const float*)d_in[18];

    float* out = (float*)d_out;

    const size_t NF = (size_t)B_ * C_ * HW_;   // 7,782,400 elements
    unsigned short* xb16 = (unsigned short*)d_ws;
    unsigned short* bA   = xb16 + NF;
    unsigned short* bB   = bA + NF;
    unsigned short* bC   = bB + NF;
    unsigned short* bD   = bC + NF;
    unsigned short* wtb0 = bD + NF;                    // 589,824 bf16
    unsigned short* wtb1 = wtb0 + (size_t)CK * C_;
    float* stats = (float*)(wtb1 + (size_t)CK * C_);   // 256 stats + 32 zbuf
    const unsigned short* zbuf = (const unsigned short*)(stats + 256);

    const dim3 convGrid2(5, 25, 4);       // dual tower, M=128 (4x32)
    const dim3 convGrid1(5, 25, 2);       // single tower
    const dim3 wprepGrid2(C_, 9, 2);
    const dim3 wprepGrid1(C_, 9, 1);
    const dim3 nhwcGrid((HW_ + 63) / 64, C_ / 64, B_);
    const dim3 gnGrid((B_ * HW_ * 32) / 256, 2);
    const dim3 deformGrid(W_ / 8, H_ / 4, 4);        // (19, 25, 4)
    const int  px_blocks = (B_ * HW_) / 64;          // 475

    to_nhwc_b16_kernel<<<nhwcGrid, 256, 0, stream>>>(x, xb16);

    // --- stage 0: xb16 -> bA (cls), bC (pts) ---
    wprep2_kernel<<<wprepGrid2, 256, 0, stream>>>(cls_w, reg_w, wtb0, wtb1, stats);
    conv3x3_mfma3_kernel<<<convGrid2, 512, 0, stream>>>(
        xb16, xb16, wtb0, wtb1, cls_b, reg_b, bA, bC, stats, zbuf, 0);
    gn2_apply_kernel<<<gnGrid, 256, 0, stream>>>(
        bA, bC, stats, cls_gn_g, cls_gn_b, reg_gn_g, reg_gn_b);

    // --- stage 1: bA -> bB, bC -> bD ---
    wprep2_kernel<<<wprepGrid2, 256, 0, stream>>>(
        cls_w + (size_t)C_ * CK, reg_w + (size_t)C_ * CK, wtb0, wtb1, stats);
    conv3x3_mfma3_kernel<<<convGrid2, 512, 0, stream>>>(
        bA, bC, wtb0, wtb1, cls_b + C_, reg_b + C_, bB, bD, stats, zbuf, 0);
    gn2_apply_kernel<<<gnGrid, 256, 0, stream>>>(
        bB, bD, stats, cls_gn_g + C_, cls_gn_b + C_, reg_gn_g + C_, reg_gn_b + C_);

    // --- stage 2: bB -> bA (clsF), bD -> bC (ptsF) ---
    wprep2_kernel<<<wprepGrid2, 256, 0, stream>>>(
        cls_w + 2 * (size_t)C_ * CK, reg_w + 2 * (size_t)C_ * CK, wtb0, wtb1, stats);
    conv3x3_mfma3_kernel<<<convGrid2, 512, 0, stream>>>(
        bB, bD, wtb0, wtb1, cls_b + 2 * C_, reg_b + 2 * C_, bA, bC, stats, zbuf, 0);
    gn2_apply_kernel<<<gnGrid, 256, 0, stream>>>(
        bA, bC, stats, cls_gn_g + 2 * C_, cls_gn_b + 2 * C_,
        reg_gn_g + 2 * C_, reg_gn_b + 2 * C_);

    // --- init branch: relu(conv3x3(ptsF=bC)) -> bD -> 1x1 -> pts_out_init ---
    wprep2_kernel<<<wprepGrid1, 256, 0, stream>>>(init_conv_w, nullptr, wtb0, nullptr, stats);
    conv3x3_mfma3_kernel<<<convGrid1, 512, 0, stream>>>(
        bC, nullptr, wtb0, nullptr, init_conv_b, nullptr, bD, nullptr, nullptr, zbuf, 1);
    conv1x1_kernel<5><<<px_blocks, 256, 0, stream>>>(
        bD, init_out_w, init_out_b, nullptr, out + OFF_INIT, 18);

    // --- both deforms in one dispatch: clsF->bB, ptsF->bD ---
    wprep2_kernel<<<wprepGrid2, 256, 0, stream>>>(cls_dcn_w, ref_dcn_w, wtb0, wtb1, stats);
    deform3_mfma_kernel<<<deformGrid, 256, 0, stream>>>(
        bA, bC, out + OFF_INIT, wtb0, wtb1, bB, bD, zbuf);

    // --- tails ---
    conv1x1_kernel<20><<<px_blocks, 256, 0, stream>>>(
        bB, cls_out_w, cls_out_b, nullptr, out, 80);
    conv1x1_kernel<5><<<px_blocks, 256, 0, stream>>>(
        bD, ref_out_w, ref_out_b, out + OFF_INIT, out + OFF_REF, 18);
}